// Round 9
// baseline (437.670 us; speedup 1.0000x reference)
//
#include <hip/hip_runtime.h>
#include <math.h>

#define B_ 2
#define N_ 1000
#define F_ 8
#define T_ 12
#define H_ 64
#define G_ 24      // B*T
#define NF_ 8000   // N*F
#define ER_ 2000
#define EC_ 24000

typedef short bf16x8 __attribute__((ext_vector_type(8)));
typedef short short4v __attribute__((ext_vector_type(4)));
typedef float f32x4 __attribute__((ext_vector_type(4)));

#define LGKM0 do { asm volatile("s_waitcnt lgkmcnt(0)" ::: "memory"); __builtin_amdgcn_sched_barrier(0); } while(0)

__device__ __forceinline__ float sigf(float x){ return 1.0f/(1.0f+__expf(-x)); }

// f32 -> bf16 (RNE)
__device__ __forceinline__ unsigned short f2b(float f){
    unsigned u = __float_as_uint(f);
    unsigned r = (u + 0x7FFFu + ((u >> 16) & 1u)) >> 16;
    return (unsigned short)r;
}
__device__ __forceinline__ float b2f(unsigned short u){
    return __uint_as_float(((unsigned)u) << 16);
}

// ---------------------------------------------------------------- ws = mean over F (4 nodes/block)
__global__ __launch_bounds__(256) void k_ws(const float* __restrict__ x, float* __restrict__ ws){
    int idx = blockIdx.x*4 + (threadIdx.x >> 6);   // g*N + n
    int h = threadIdx.x & 63;
    int g = idx / N_, n = idx % N_;
    int b = g / T_, t = g % T_;
    const float* base = x + ((size_t)(b*N_+n)*F_*T_ + t)*H_ + h;
    float s = 0.f;
    #pragma unroll
    for (int f=0; f<F_; ++f) s += base[(size_t)f*T_*H_];
    ws[(size_t)idx*H_ + h] = s * (1.0f/F_);
}

// ---------------------------------------------------------------- CSR build: mw + histogram
__global__ __launch_bounds__(256) void k_mwhist(const int* __restrict__ c_dst, const int* __restrict__ r_dst,
                                                const float* __restrict__ c_ew, const float* __restrict__ c_lw,
                                                const float* __restrict__ c_gate,
                                                const float* __restrict__ r_ew, const float* __restrict__ r_lw,
                                                const float* __restrict__ r_gate,
                                                float* __restrict__ mw_c, float* __restrict__ mw_r,
                                                int* __restrict__ cnt_c, int* __restrict__ cnt_r){
    int i = blockIdx.x*256 + threadIdx.x;
    if (i < EC_){
        float gs = sigf(c_gate[0]);
        mw_c[i] = gs*c_ew[i] + (1.f-gs)*sigf(c_lw[i]);
        atomicAdd(&cnt_c[c_dst[i]], 1);
    } else if (i < EC_+ER_){
        int e = i - EC_;
        float gs = sigf(r_gate[0]);
        mw_r[e] = gs*r_ew[e] + (1.f-gs)*sigf(r_lw[e]);
        atomicAdd(&cnt_r[r_dst[e]], 1);
    }
}

// ---------------------------------------------------------------- CSR build: exclusive scan
__global__ __launch_bounds__(256) void k_scan(const int* __restrict__ cnt_c, int* __restrict__ off_c, int* __restrict__ cur_c,
                                              const int* __restrict__ cnt_r, int* __restrict__ off_r, int* __restrict__ cur_r){
    const int n = (blockIdx.x==0) ? NF_ : N_;
    const int* cnt = (blockIdx.x==0) ? cnt_c : cnt_r;
    int* off = (blockIdx.x==0) ? off_c : off_r;
    int* cur = (blockIdx.x==0) ? cur_c : cur_r;
    __shared__ int part[256];
    int tid = threadIdx.x;
    int tpt = (n + 255) / 256;
    int i0 = tid * tpt;
    int s = 0;
    for (int i=0;i<tpt;++i){ int idx=i0+i; if (idx<n) s += cnt[idx]; }
    part[tid] = s;
    __syncthreads();
    if (tid == 0){
        int run = 0;
        for (int j=0;j<256;++j){ int t = part[j]; part[j] = run; run += t; }
        off[n] = run;
    }
    __syncthreads();
    int run = part[tid];
    for (int i=0;i<tpt;++i){
        int idx = i0+i;
        if (idx < n){ off[idx] = run; cur[idx] = run; run += cnt[idx]; }
    }
}

// ---------------------------------------------------------------- CSR build: fill edge lists
__global__ __launch_bounds__(256) void k_fill(const int* __restrict__ c_dst, const int* __restrict__ r_dst,
                                              int* __restrict__ cur_c, int* __restrict__ cur_r,
                                              int* __restrict__ eidx_c, int* __restrict__ eidx_r){
    int i = blockIdx.x*256 + threadIdx.x;
    if (i < EC_){
        int p = atomicAdd(&cur_c[c_dst[i]], 1);
        eidx_c[p] = i;
    } else if (i < EC_+ER_){
        int e = i - EC_;
        int p = atomicAdd(&cur_r[r_dst[e]], 1);
        eidx_r[p] = e;
    }
}

// ---------------------------------------------------------------- gather-aggregate (bf16 in/out), no atomics
__global__ __launch_bounds__(256) void k_gaggr(const unsigned short* __restrict__ y,
                                               const int* __restrict__ src,
                                               const int* __restrict__ eidx,
                                               const int* __restrict__ off,
                                               const float* __restrict__ mw,
                                               unsigned short* __restrict__ aggr,
                                               int nseg, int cpx){
    int l = threadIdx.x & 63;
    int wg = (blockIdx.x & 7)*cpx + (blockIdx.x >> 3);
    int idx = wg*4 + (threadIdx.x >> 6);   // g*nseg + d
    int g = idx / nseg, d = idx % nseg;
    int o0 = off[d], o1 = off[d+1];
    float acc = 0.f;
    for (int p=o0; p<o1; ++p){
        int e = eidx[p];
        acc += mw[e] * b2f(y[((size_t)g*nseg + src[e])*64 + l]);
    }
    aggr[(size_t)idx*64 + l] = f2b(acc);
}

// ---------------------------------------------------------------- weight prep: bf16 W^T panels
// Q columns of Wqkv pre-scaled by 0.25 (exact exponent shift).
__global__ __launch_bounds__(256) void k_prepw(const float* __restrict__ Wqkv,
                                               const float* __restrict__ Wo,
                                               const float* __restrict__ W1,
                                               const float* __restrict__ W2,
                                               const float* __restrict__ csWlin,
                                               const float* __restrict__ rvWlin,
                                               const float* __restrict__ csWupd,
                                               const float* __restrict__ rvWupd,
                                               const float* __restrict__ fuW1,
                                               const float* __restrict__ fuW2,
                                               unsigned short* __restrict__ wt){
    int i = blockIdx.x*256 + threadIdx.x;
    if      (i < 12288){ int n=i>>6, k=i&63; float v = Wqkv[k*192+n]; if (n < 64) v *= 0.25f; wt[i] = f2b(v); }
    else if (i < 16384){ int z=i-12288; int n=z>>6, k=z&63; wt[i] = f2b(Wo[k*64+n]); }
    else if (i < 32768){ int z=i-16384; int n=z>>6, k=z&63; wt[i] = f2b(W1[k*256+n]); }
    else if (i < 49152){ int z=i-32768; int n=z>>8, k=z&255; wt[i] = f2b(W2[k*64+n]); }
    else if (i < 53248){ int z=i-49152; int n=z>>6, k=z&63; wt[i] = f2b(csWlin[k*64+n]); }
    else if (i < 57344){ int z=i-53248; int n=z>>6, k=z&63; wt[i] = f2b(rvWlin[k*64+n]); }
    else if (i < 65536){ int z=i-57344; int n=z>>7, k=z&127; wt[i] = f2b(csWupd[k*64+n]); }
    else if (i < 73728){ int z=i-65536; int n=z>>7, k=z&127; wt[i] = f2b(rvWupd[k*64+n]); }
    else if (i < 81920){ int z=i-73728; int n=z>>7, k=z&127; wt[i] = f2b(fuW1[k*64+n]); }
    else if (i < 86016){ int z=i-81920; int n=z>>6, k=z&63; wt[i] = f2b(fuW2[k*64+n]); }
}

// ---------------------------------------------------------------- MFMA y = rows @ W(64x64) + b  (bf16 out)
template<bool GATHER>
__global__ __launch_bounds__(256) void k_lin16(const float* __restrict__ xin,
                                               const float* __restrict__ x,
                                               const unsigned short* __restrict__ wT,  // [64 n][64 k]
                                               const float* __restrict__ bias,
                                               unsigned short* __restrict__ y){
    __shared__ unsigned short XBs[4][16*72];
    int w = threadIdx.x>>6, l = threadIdx.x&63;
    int lr = l&15, lg = l>>4;
    unsigned short* XB = XBs[w];
    int r0 = (blockIdx.x*4 + w)*16;
    #pragma unroll
    for (int i=0;i<16;++i){
        int rr = r0+i;
        float v;
        if (GATHER){
            int g = rr/NF_, j = rr%NF_;
            int b = g/T_, t = g%T_, n = j/F_, f = j%F_;
            v = x[((size_t)((b*N_+n)*F_+f)*T_ + t)*64 + l];
        } else {
            v = xin[(size_t)rr*64 + l];
        }
        XB[i*72 + l] = f2b(v);
    }
    LGKM0;
    bf16x8 a0 = *(const bf16x8*)&XB[lr*72 + lg*8];
    bf16x8 a1 = *(const bf16x8*)&XB[lr*72 + 32 + lg*8];
    f32x4 acc[4];
    #pragma unroll
    for (int ct=0;ct<4;++ct) acc[ct] = (f32x4){0.f,0.f,0.f,0.f};
    #pragma unroll
    for (int ct=0;ct<4;++ct){
        bf16x8 b0 = *(const bf16x8*)&wT[(ct*16+lr)*64 + lg*8];
        bf16x8 b1 = *(const bf16x8*)&wT[(ct*16+lr)*64 + 32 + lg*8];
        acc[ct] = __builtin_amdgcn_mfma_f32_16x16x32_bf16(a0, b0, acc[ct], 0,0,0);
        acc[ct] = __builtin_amdgcn_mfma_f32_16x16x32_bf16(a1, b1, acc[ct], 0,0,0);
    }
    #pragma unroll
    for (int ct=0;ct<4;++ct){
        float bv = bias[ct*16+lr];
        #pragma unroll
        for (int i=0;i<4;++i)
            y[(size_t)(r0+lg*4+i)*64 + ct*16+lr] = f2b(acc[ct][i] + bv);
    }
}

// ---------------------------------------------------------------- MFMA u = relu([aggr|ws] @ Wu(128x64) + b)  (river; bf16 aggr in, bf16 out)
__global__ __launch_bounds__(256) void k_upd16(const unsigned short* __restrict__ aggr,
                                               const float* __restrict__ xin,
                                               const unsigned short* __restrict__ wT,  // [64 n][128 k]
                                               const float* __restrict__ bu,
                                               unsigned short* __restrict__ u){
    __shared__ unsigned short XBs[4][16*136];
    int w = threadIdx.x>>6, l = threadIdx.x&63;
    int lr = l&15, lg = l>>4;
    unsigned short* XB = XBs[w];
    int r0 = (blockIdx.x*4 + w)*16;
    #pragma unroll
    for (int i=0;i<16;++i){
        int rr = r0+i;
        XB[i*136 + l]      = aggr[(size_t)rr*64 + l];
        XB[i*136 + 64 + l] = f2b(xin[(size_t)rr*64 + l]);
    }
    LGKM0;
    bf16x8 a[4];
    #pragma unroll
    for (int kk=0;kk<4;++kk) a[kk] = *(const bf16x8*)&XB[lr*136 + kk*32 + lg*8];
    f32x4 acc[4];
    #pragma unroll
    for (int ct=0;ct<4;++ct) acc[ct] = (f32x4){0.f,0.f,0.f,0.f};
    #pragma unroll
    for (int ct=0;ct<4;++ct){
        #pragma unroll
        for (int kk=0;kk<4;++kk){
            bf16x8 b0 = *(const bf16x8*)&wT[(ct*16+lr)*128 + kk*32 + lg*8];
            acc[ct] = __builtin_amdgcn_mfma_f32_16x16x32_bf16(a[kk], b0, acc[ct], 0,0,0);
        }
    }
    #pragma unroll
    for (int ct=0;ct<4;++ct){
        float bv = bu[ct*16+lr];
        #pragma unroll
        for (int i=0;i<4;++i)
            u[(size_t)(r0+lg*4+i)*64 + ct*16+lr] = f2b(fmaxf(acc[ct][i] + bv, 0.f));
    }
}

// ---------------------------------------------------------------- fused causal-update + fusion MLP (bf16 in/out)
__global__ __launch_bounds__(256) void k_updfus(const unsigned short* __restrict__ aggr,
                                                const float* __restrict__ x,
                                                const unsigned short* __restrict__ wuT,  // [64][128]
                                                const float* __restrict__ bu,
                                                const unsigned short* __restrict__ wsu,
                                                const unsigned short* __restrict__ w1T,  // [64][128]
                                                const float* __restrict__ b1,
                                                const unsigned short* __restrict__ w2T,  // [64][64]
                                                const float* __restrict__ b2,
                                                unsigned short* __restrict__ fused){
    __shared__ unsigned short XBs[4][16*136];
    __shared__ unsigned short X2s[4][16*136];
    int w = threadIdx.x>>6, l = threadIdx.x&63;
    int lr = l&15, lg = l>>4;
    unsigned short* XB = XBs[w];
    unsigned short* X2 = X2s[w];
    int r0 = (blockIdx.x*4 + w)*16;
    #pragma unroll
    for (int i=0;i<16;++i){
        int rr = r0+i;
        int g = rr/NF_, j = rr%NF_;
        int b = g/T_, t = g%T_, n = j/F_, f = j%F_;
        XB[i*136 + l]      = aggr[(size_t)rr*64 + l];
        XB[i*136 + 64 + l] = f2b(x[((size_t)((b*N_+n)*F_+f)*T_ + t)*64 + l]);
        X2[i*136 + 64 + l] = wsu[((size_t)g*N_ + n)*64 + l];
    }
    LGKM0;
    {
        bf16x8 a[4];
        #pragma unroll
        for (int kk=0;kk<4;++kk) a[kk] = *(const bf16x8*)&XB[lr*136 + kk*32 + lg*8];
        f32x4 acc[4];
        #pragma unroll
        for (int ct=0;ct<4;++ct) acc[ct] = (f32x4){0.f,0.f,0.f,0.f};
        #pragma unroll
        for (int ct=0;ct<4;++ct){
            #pragma unroll
            for (int kk=0;kk<4;++kk){
                bf16x8 b0 = *(const bf16x8*)&wuT[(ct*16+lr)*128 + kk*32 + lg*8];
                acc[ct] = __builtin_amdgcn_mfma_f32_16x16x32_bf16(a[kk], b0, acc[ct], 0,0,0);
            }
        }
        #pragma unroll
        for (int ct=0;ct<4;++ct){
            float bv = bu[ct*16+lr];
            #pragma unroll
            for (int i=0;i<4;++i)
                X2[(lg*4+i)*136 + ct*16+lr] = f2b(fmaxf(acc[ct][i] + bv, 0.f));
        }
    }
    LGKM0;
    {
        bf16x8 a[4];
        #pragma unroll
        for (int kk=0;kk<4;++kk) a[kk] = *(const bf16x8*)&X2[lr*136 + kk*32 + lg*8];
        f32x4 acc[4];
        #pragma unroll
        for (int ct=0;ct<4;++ct) acc[ct] = (f32x4){0.f,0.f,0.f,0.f};
        #pragma unroll
        for (int ct=0;ct<4;++ct){
            #pragma unroll
            for (int kk=0;kk<4;++kk){
                bf16x8 b0 = *(const bf16x8*)&w1T[(ct*16+lr)*128 + kk*32 + lg*8];
                acc[ct] = __builtin_amdgcn_mfma_f32_16x16x32_bf16(a[kk], b0, acc[ct], 0,0,0);
            }
        }
        #pragma unroll
        for (int ct=0;ct<4;++ct){
            float bv = b1[ct*16+lr];
            #pragma unroll
            for (int i=0;i<4;++i)
                XB[(lg*4+i)*136 + ct*16+lr] = f2b(fmaxf(acc[ct][i] + bv, 0.f));
        }
    }
    LGKM0;
    {
        bf16x8 h0 = *(const bf16x8*)&XB[lr*136 + lg*8];
        bf16x8 h1 = *(const bf16x8*)&XB[lr*136 + 32 + lg*8];
        f32x4 acc[4];
        #pragma unroll
        for (int ct=0;ct<4;++ct) acc[ct] = (f32x4){0.f,0.f,0.f,0.f};
        #pragma unroll
        for (int ct=0;ct<4;++ct){
            bf16x8 b0 = *(const bf16x8*)&w2T[(ct*16+lr)*64 + lg*8];
            bf16x8 b1v= *(const bf16x8*)&w2T[(ct*16+lr)*64 + 32 + lg*8];
            acc[ct] = __builtin_amdgcn_mfma_f32_16x16x32_bf16(h0, b0, acc[ct], 0,0,0);
            acc[ct] = __builtin_amdgcn_mfma_f32_16x16x32_bf16(h1, b1v, acc[ct], 0,0,0);
        }
        #pragma unroll
        for (int ct=0;ct<4;++ct){
            float bv = b2[ct*16+lr];
            #pragma unroll
            for (int i=0;i<4;++i)
                fused[(size_t)(r0+lg*4+i)*64 + ct*16+lr] = f2b(acc[ct][i] + bv);
        }
    }
}

// ---------------------------------------------------------------- MFMA temporal transformer
// V^T stashed in XB (LN1-out dead once a0/a1 in regs): VT'[d][t] = XB[(d&15)*72 + (d>>4)*16 + t].
// Per-head O-write overwrites only that head's own (consumed) V slice.
#define XSTR 72    // XB stride (shorts)
#define SSTR 136   // SC stride (shorts): Q cols 0-63, K cols 64-127; aliased as HID [16][136]

__global__ __launch_bounds__(256) void k_xformer(
    const unsigned short* __restrict__ fused,
    const unsigned short* __restrict__ wtq,   // [192][64] bf16 (n,k), Q-part pre-scaled 0.25
    const unsigned short* __restrict__ wto,   // [64][64]
    const unsigned short* __restrict__ wt1,   // [256][64]
    const unsigned short* __restrict__ wt2,   // [64][256]
    const float* __restrict__ bqkv, const float* __restrict__ bo,
    const float* __restrict__ fb1,  const float* __restrict__ fb2,
    const float* __restrict__ ln1g, const float* __restrict__ ln1b,
    const float* __restrict__ ln2g, const float* __restrict__ ln2b,
    float* __restrict__ out)
{
    __shared__ unsigned short XBs[4][16*XSTR];
    __shared__ unsigned short SCs[4][16*SSTR];

    int w  = threadIdx.x >> 6;
    int l  = threadIdx.x & 63;
    int lr = l & 15;
    int lg = l >> 4;

    unsigned short* XB  = XBs[w];
    unsigned short* SC  = SCs[w];
    unsigned short* HID = SCs[w];

    int gs = blockIdx.x*4 + w;
    int bb = gs / NF_, j = gs % NF_;
    const unsigned short* fp = fused + ((size_t)bb*T_*NF_ + j)*64;

    float res[4][4];
    #pragma unroll
    for (int nt=0;nt<4;++nt)
        #pragma unroll
        for (int i=0;i<4;++i){
            int t = lg*4+i;
            res[nt][i] = (t < 12) ? b2f(fp[(size_t)t*NF_*64 + nt*16 + lr]) : 0.f;
        }

    // LN1 -> XB
    {
        float sm[4], sq[4];
        #pragma unroll
        for (int i=0;i<4;++i){
            sm[i] = res[0][i]+res[1][i]+res[2][i]+res[3][i];
            sq[i] = res[0][i]*res[0][i]+res[1][i]*res[1][i]+res[2][i]*res[2][i]+res[3][i]*res[3][i];
        }
        #pragma unroll
        for (int m=1;m<16;m<<=1){
            #pragma unroll
            for (int i=0;i<4;++i){
                sm[i] += __shfl_xor(sm[i], m, 64);
                sq[i] += __shfl_xor(sq[i], m, 64);
            }
        }
        #pragma unroll
        for (int nt=0;nt<4;++nt){
            float gg = ln1g[nt*16+lr], oo = ln1b[nt*16+lr];
            #pragma unroll
            for (int i=0;i<4;++i){
                float mn = sm[i]*(1.0f/64.0f);
                float var = sq[i]*(1.0f/64.0f) - mn*mn;
                float rs = rsqrtf(var + 1e-5f);
                XB[(lg*4+i)*XSTR + nt*16 + lr] = f2b((res[nt][i]-mn)*rs*gg + oo);
            }
        }
    }
    LGKM0;

    // QKV GEMM: Q,K -> SC; V -> transposed into XB (a0/a1 already in regs)
    {
        bf16x8 a0 = *(const bf16x8*)&XB[lr*XSTR + 0*32 + lg*8];
        bf16x8 a1 = *(const bf16x8*)&XB[lr*XSTR + 1*32 + lg*8];
        LGKM0;   // a0/a1 landed in regs before V overwrites XB
        #pragma unroll
        for (int p=0;p<3;++p){
            f32x4 acc[4];
            #pragma unroll
            for (int c=0;c<4;++c) acc[c] = (f32x4){0.f,0.f,0.f,0.f};
            #pragma unroll
            for (int c=0;c<4;++c){
                int ct = p*4 + c;
                bf16x8 b0 = *(const bf16x8*)&wtq[(ct*16+lr)*64 + 0*32 + lg*8];
                bf16x8 b1v= *(const bf16x8*)&wtq[(ct*16+lr)*64 + 1*32 + lg*8];
                acc[c] = __builtin_amdgcn_mfma_f32_16x16x32_bf16(a0, b0, acc[c], 0,0,0);
                acc[c] = __builtin_amdgcn_mfma_f32_16x16x32_bf16(a1, b1v, acc[c], 0,0,0);
            }
            if (p < 2){
                #pragma unroll
                for (int c=0;c<4;++c){
                    int ct = p*4 + c;
                    float bv = bqkv[ct*16+lr];
                    if (p == 0) bv *= 0.25f;     // match pre-scaled Q weights
                    #pragma unroll
                    for (int i=0;i<4;++i)
                        SC[(lg*4+i)*SSTR + p*64 + c*16 + lr] = f2b(acc[c][i] + bv);
                }
            } else {
                #pragma unroll
                for (int c=0;c<4;++c){
                    float bv = bqkv[128 + c*16 + lr];
                    short4v vv;
                    #pragma unroll
                    for (int i=0;i<4;++i) vv[i] = (short)f2b(acc[c][i] + bv);
                    // VT'[d=c*16+lr][t=lg*4..+3]
                    *(short4v*)&XB[lr*XSTR + c*16 + lg*4] = vv;
                }
            }
        }
    }
    LGKM0;

    // MFMA attention per head: S^T = K·Q^T ; P^T ; O^T = V^T·P^T
    {
        const bf16x8 bz = (bf16x8){0,0,0,0,0,0,0,0};
        #pragma unroll
        for (int hd=0; hd<4; ++hd){
            bf16x8 ak = bz, bq = bz;
            if (lg < 2){
                ak = *(const bf16x8*)&SC[lr*SSTR + 64 + hd*16 + lg*8];  // K[kt=lr][d']
                bq = *(const bf16x8*)&SC[lr*SSTR +      hd*16 + lg*8];  // Q[qt=lr][d']
            }
            f32x4 st = __builtin_amdgcn_mfma_f32_16x16x32_bf16(ak, bq, (f32x4){0.f,0.f,0.f,0.f}, 0,0,0);
            float s0=st[0], s1v=st[1], s2=st[2], s3=st[3];
            if (lg == 3){ s0=s1v=s2=s3=-1e30f; }   // kt 12..15 invalid
            float mx = fmaxf(fmaxf(s0,s1v), fmaxf(s2,s3));
            mx = fmaxf(mx, __shfl_xor(mx, 16, 64));
            mx = fmaxf(mx, __shfl_xor(mx, 32, 64));
            float p0 = __expf(s0-mx), p1 = __expf(s1v-mx), p2 = __expf(s2-mx), p3 = __expf(s3-mx);
            float den = p0+p1+p2+p3;
            den += __shfl_xor(den, 16, 64);
            den += __shfl_xor(den, 32, 64);
            float inv = __builtin_amdgcn_rcpf(den);
            float q0 = __shfl_down(p0, 16, 64), q1 = __shfl_down(p1, 16, 64);
            float q2 = __shfl_down(p2, 16, 64), q3 = __shfl_down(p3, 16, 64);
            bf16x8 pb;
            {
                float lo0 = (lg==0)? p0 : (lg==1)? q0 : 0.f;
                float lo1 = (lg==0)? p1 : (lg==1)? q1 : 0.f;
                float lo2 = (lg==0)? p2 : (lg==1)? q2 : 0.f;
                float lo3 = (lg==0)? p3 : (lg==1)? q3 : 0.f;
                float hi0 = (lg==0)? q0 : 0.f;
                float hi1 = (lg==0)? q1 : 0.f;
                float hi2 = (lg==0)? q2 : 0.f;
                float hi3 = (lg==0)? q3 : 0.f;
                pb[0]=(short)f2b(lo0); pb[1]=(short)f2b(lo1); pb[2]=(short)f2b(lo2); pb[3]=(short)f2b(lo3);
                pb[4]=(short)f2b(hi0); pb[5]=(short)f2b(hi1); pb[6]=(short)f2b(hi2); pb[7]=(short)f2b(hi3);
            }
            // A = V^T rows d'=hd*16+lr, k=kt: VT' in XB
            bf16x8 av = bz;
            if (lg < 2) av = *(const bf16x8*)&XB[lr*XSTR + hd*16 + lg*8];
            f32x4 ot = __builtin_amdgcn_mfma_f32_16x16x32_bf16(av, pb, (f32x4){0.f,0.f,0.f,0.f}, 0,0,0);
            // write O[qt=lr][hd*16 + lg*4..+3] — overwrites head hd's own V slice (consumed)
            short4v ow;
            #pragma unroll
            for (int i=0;i<4;++i) ow[i] = (short)f2b(ot[i]*inv);
            *(short4v*)&XB[lr*XSTR + hd*16 + lg*4] = ow;
        }
    }
    LGKM0;

    // proj + residual -> s1
    float s1[4][4];
    {
        bf16x8 a0 = *(const bf16x8*)&XB[lr*XSTR + 0*32 + lg*8];
        bf16x8 a1 = *(const bf16x8*)&XB[lr*XSTR + 1*32 + lg*8];
        f32x4 pacc[4];
        #pragma unroll
        for (int ct=0;ct<4;++ct) pacc[ct] = (f32x4){0.f,0.f,0.f,0.f};
        #pragma unroll
        for (int ct=0;ct<4;++ct){
            bf16x8 b0 = *(const bf16x8*)&wto[(ct*16+lr)*64 + 0*32 + lg*8];
            bf16x8 b1v= *(const bf16x8*)&wto[(ct*16+lr)*64 + 1*32 + lg*8];
            pacc[ct] = __builtin_amdgcn_mfma_f32_16x16x32_bf16(a0, b0, pacc[ct], 0,0,0);
            pacc[ct] = __builtin_amdgcn_mfma_f32_16x16x32_bf16(a1, b1v, pacc[ct], 0,0,0);
        }
        #pragma unroll
        for (int ct=0;ct<4;++ct){
            float bv = bo[ct*16+lr];
            #pragma unroll
            for (int i=0;i<4;++i)
                s1[ct][i] = res[ct][i] + pacc[ct][i] + bv;
        }
    }

    // LN2 -> XB
    {
        float sm[4], sq[4];
        #pragma unroll
        for (int i=0;i<4;++i){
            sm[i] = s1[0][i]+s1[1][i]+s1[2][i]+s1[3][i];
            sq[i] = s1[0][i]*s1[0][i]+s1[1][i]*s1[1][i]+s1[2][i]*s1[2][i]+s1[3][i]*s1[3][i];
        }
        #pragma unroll
        for (int m=1;m<16;m<<=1){
            #pragma unroll
            for (int i=0;i<4;++i){
                sm[i] += __shfl_xor(sm[i], m, 64);
                sq[i] += __shfl_xor(sq[i], m, 64);
            }
        }
        #pragma unroll
        for (int nt=0;nt<4;++nt){
            float gg = ln2g[nt*16+lr], oo = ln2b[nt*16+lr];
            #pragma unroll
            for (int i=0;i<4;++i){
                float mn = sm[i]*(1.0f/64.0f);
                float var = sq[i]*(1.0f/64.0f) - mn*mn;
                float rs = rsqrtf(var + 1e-5f);
                XB[(lg*4+i)*XSTR + nt*16 + lr] = f2b((s1[nt][i]-mn)*rs*gg + oo);
            }
        }
    }
    LGKM0;

    // FFN: two 128-wide halves; gelu via x*sigmoid
    f32x4 oacc[4];
    #pragma unroll
    for (int ct=0;ct<4;++ct) oacc[ct] = (f32x4){0.f,0.f,0.f,0.f};
    {
        bf16x8 a0 = *(const bf16x8*)&XB[lr*XSTR + 0*32 + lg*8];
        bf16x8 a1 = *(const bf16x8*)&XB[lr*XSTR + 1*32 + lg*8];
        #pragma unroll
        for (int half=0; half<2; ++half){
            LGKM0;   // HID region reuse guard
            #pragma unroll
            for (int q=0; q<2; ++q){
                f32x4 facc[4];
                #pragma unroll
                for (int c=0;c<4;++c) facc[c] = (f32x4){0.f,0.f,0.f,0.f};
                #pragma unroll
                for (int c=0;c<4;++c){
                    int ct = half*8 + q*4 + c;
                    bf16x8 b0 = *(const bf16x8*)&wt1[(ct*16+lr)*64 + 0*32 + lg*8];
                    bf16x8 b1v= *(const bf16x8*)&wt1[(ct*16+lr)*64 + 1*32 + lg*8];
                    facc[c] = __builtin_amdgcn_mfma_f32_16x16x32_bf16(a0, b0, facc[c], 0,0,0);
                    facc[c] = __builtin_amdgcn_mfma_f32_16x16x32_bf16(a1, b1v, facc[c], 0,0,0);
                }
                #pragma unroll
                for (int c=0;c<4;++c){
                    int ct = half*8 + q*4 + c;
                    float bv = fb1[ct*16+lr];
                    #pragma unroll
                    for (int i=0;i<4;++i){
                        float xv = facc[c][i] + bv;
                        float x2 = xv*xv;
                        float z  = xv*(1.5957691216f + 0.0713548162f*x2);
                        float ez = __expf(-z);
                        HID[(lg*4+i)*SSTR + (q*4+c)*16 + lr] = f2b(xv * __builtin_amdgcn_rcpf(1.0f + ez));
                    }
                }
            }
            LGKM0;
            #pragma unroll
            for (int ks=0;ks<4;++ks){
                bf16x8 af = *(const bf16x8*)&HID[lr*SSTR + ks*32 + lg*8];
                #pragma unroll
                for (int ct=0;ct<4;++ct){
                    bf16x8 bfr = *(const bf16x8*)&wt2[(ct*16+lr)*256 + half*128 + ks*32 + lg*8];
                    oacc[ct] = __builtin_amdgcn_mfma_f32_16x16x32_bf16(af, bfr, oacc[ct], 0,0,0);
                }
            }
        }
    }

    // residual + mean over t
    #pragma unroll
    for (int ct=0;ct<4;++ct){
        float bv = fb2[ct*16+lr];
        float part = 0.f;
        #pragma unroll
        for (int i=0;i<4;++i){
            if (lg*4+i < 12) part += s1[ct][i] + oacc[ct][i] + bv;
        }
        part += __shfl_xor(part, 16, 64);
        part += __shfl_xor(part, 32, 64);
        if (lg == 0) out[(size_t)gs*64 + ct*16 + lr] = part*(1.0f/12.0f);
    }
}

// ----------------------------------------------------------------
extern "C" void kernel_launch(void* const* d_in, const int* in_sizes, int n_in,
                              void* d_out, int out_size, void* d_ws, size_t ws_size,
                              hipStream_t stream) {
    const float* x      = (const float*)d_in[0];
    const int*   r_ei   = (const int*)  d_in[1];
    const float* r_ea   = (const float*)d_in[2];
    const int*   c_ei   = (const int*)  d_in[3];
    const float* c_ew   = (const float*)d_in[4];
    const float* rvWlin = (const float*)d_in[5];
    const float* rvblin = (const float*)d_in[6];
    const float* rvWupd = (const float*)d_in[7];
    const float* rvbupd = (const float*)d_in[8];
    const float* rvgate = (const float*)d_in[9];
    const float* rvlw   = (const float*)d_in[10];
    const float* csWlin = (const float*)d_in[11];
    const float* csblin = (const float*)d_in[12];
    const float* csWupd = (const float*)d_in[13];
    const float* csbupd = (const float*)d_in[14];
    const float* csgate = (const float*)d_in[15];
    const float* cslw   = (const float*)d_in[16];
    const float* fuW1   = (const float*)d_in[17];
    const float* fub1   = (const float*)d_in[18];
    const float* fuW2   = (const float*)d_in[19];
    const float* fub2   = (const float*)d_in[20];
    const float* ln1g   = (const float*)d_in[21];
    const float* ln1b   = (const float*)d_in[22];
    const float* ln2g   = (const float*)d_in[23];
    const float* ln2b   = (const float*)d_in[24];
    const float* Wqkv   = (const float*)d_in[25];
    const float* bqkv   = (const float*)d_in[26];
    const float* Wo     = (const float*)d_in[27];
    const float* bo     = (const float*)d_in[28];
    const float* ffW1   = (const float*)d_in[29];
    const float* ffb1   = (const float*)d_in[30];
    const float* ffW2   = (const float*)d_in[31];
    const float* ffb2   = (const float*)d_in[32];

    float* wsp  = (float*)d_ws;
    unsigned short* FNY_b = (unsigned short*)wsp;                    // causal y bf16, then FUSED bf16
    unsigned short* FNA_b = (unsigned short*)(wsp + 12288000);       // causal aggr bf16
    float* WS   = wsp + 24576000;                                    // watershed mean fp32
    unsigned short* WSY_b = (unsigned short*)(wsp + 26112000);       // river y bf16
    unsigned short* WSA_b = (unsigned short*)(wsp + 27648000);       // river aggr bf16
    float* WSU  = wsp + 29184000;                                    // CSR scratch, then river u bf16
    unsigned short* WSU_b = (unsigned short*)WSU;
    unsigned short* wt = (unsigned short*)(wsp + 30720000);
    float* outp = (float*)d_out;

    int* ibase  = (int*)WSU;
    int* cnt_c  = ibase;
    int* cnt_r  = ibase + 8000;
    int* off_c  = ibase + 9000;
    int* off_r  = ibase + 17001;
    int* cur_c  = ibase + 18002;
    int* cur_r  = ibase + 26002;
    int* eidx_c = ibase + 27002;
    int* eidx_r = ibase + 51002;
    float* mw_c = (float*)(ibase + 53002);
    float* mw_r = (float*)(ibase + 77002);

    const int* c_src = c_ei;
    const int* c_dst = c_ei + EC_;
    const int* r_src = r_ei;
    const int* r_dst = r_ei + ER_;

    hipMemsetAsync(cnt_c, 0, 9000*sizeof(int), stream);

    k_prepw<<<336, 256, 0, stream>>>(Wqkv, Wo, ffW1, ffW2, csWlin, rvWlin, csWupd, rvWupd,
                                     fuW1, fuW2, wt);
    k_mwhist<<<(EC_+ER_+255)/256, 256, 0, stream>>>(c_dst, r_dst, c_ew, cslw, csgate,
                                                    r_ea, rvlw, rvgate, mw_c, mw_r, cnt_c, cnt_r);
    k_scan<<<2, 256, 0, stream>>>(cnt_c, off_c, cur_c, cnt_r, off_r, cur_r);
    k_fill<<<(EC_+ER_+255)/256, 256, 0, stream>>>(c_dst, r_dst, cur_c, cur_r, eidx_c, eidx_r);

    k_ws<<<(G_*N_)/4, 256, 0, stream>>>(x, WS);
    k_lin16<false><<<(G_*N_)/64, 256, 0, stream>>>(WS, nullptr, wt+53248, rvblin, WSY_b);
    k_lin16<true ><<<(G_*NF_)/64, 256, 0, stream>>>(nullptr, x, wt+49152, csblin, FNY_b);

    k_gaggr<<<(G_*N_)/4, 256, 0, stream>>>(WSY_b, r_src, eidx_r, off_r, mw_r, WSA_b, N_, (G_*N_)/4/8);
    k_gaggr<<<(G_*NF_)/4, 256, 0, stream>>>(FNY_b, c_src, eidx_c, off_c, mw_c, FNA_b, NF_, (G_*NF_)/4/8);

    // river update (clobbers CSR scratch -> OK, consumers done)
    k_upd16<<<(G_*N_)/64, 256, 0, stream>>>(WSA_b, WS, wt+65536, rvbupd, WSU_b);

    // fused causal update + fusion MLP -> FUSED bf16 (into FNY region)
    k_updfus<<<(G_*NF_)/64, 256, 0, stream>>>(FNA_b, x, wt+57344, csbupd, WSU_b,
                                              wt+73728, fub1, wt+81920, fub2, FNY_b);

    k_xformer<<<(B_*N_*F_)/4, 256, 0, stream>>>(FNY_b,
                                                wt, wt+12288, wt+16384, wt+32768,
                                                bqkv, bo, ffb1, ffb2,
                                                ln1g, ln1b, ln2g, ln2b,
                                                outp);
}

// Round 10
// 362.620 us; speedup vs baseline: 1.2070x; 1.2070x over previous
//
#include <hip/hip_runtime.h>
#include <math.h>

#define B_ 2
#define N_ 1000
#define F_ 8
#define T_ 12
#define H_ 64
#define G_ 24      // B*T
#define NF_ 8000   // N*F
#define ER_ 2000
#define EC_ 24000

typedef short bf16x8 __attribute__((ext_vector_type(8)));
typedef short short4v __attribute__((ext_vector_type(4)));
typedef float f32x4 __attribute__((ext_vector_type(4)));

#define LGKM0 do { asm volatile("s_waitcnt lgkmcnt(0)" ::: "memory"); __builtin_amdgcn_sched_barrier(0); } while(0)

__device__ __forceinline__ float sigf(float x){ return 1.0f/(1.0f+__expf(-x)); }

// f32 -> bf16 (RNE)
__device__ __forceinline__ unsigned short f2b(float f){
    unsigned u = __float_as_uint(f);
    unsigned r = (u + 0x7FFFu + ((u >> 16) & 1u)) >> 16;
    return (unsigned short)r;
}
__device__ __forceinline__ float b2f(unsigned short u){
    return __uint_as_float(((unsigned)u) << 16);
}

// ---------------------------------------------------------------- CSR build: mw + histogram
__global__ __launch_bounds__(256) void k_mwhist(const int* __restrict__ c_dst, const int* __restrict__ r_dst,
                                                const float* __restrict__ c_ew, const float* __restrict__ c_lw,
                                                const float* __restrict__ c_gate,
                                                const float* __restrict__ r_ew, const float* __restrict__ r_lw,
                                                const float* __restrict__ r_gate,
                                                float* __restrict__ mw_c, float* __restrict__ mw_r,
                                                int* __restrict__ cnt_c, int* __restrict__ cnt_r){
    int i = blockIdx.x*256 + threadIdx.x;
    if (i < EC_){
        float gs = sigf(c_gate[0]);
        mw_c[i] = gs*c_ew[i] + (1.f-gs)*sigf(c_lw[i]);
        atomicAdd(&cnt_c[c_dst[i]], 1);
    } else if (i < EC_+ER_){
        int e = i - EC_;
        float gs = sigf(r_gate[0]);
        mw_r[e] = gs*r_ew[e] + (1.f-gs)*sigf(r_lw[e]);
        atomicAdd(&cnt_r[r_dst[e]], 1);
    }
}

// ---------------------------------------------------------------- CSR build: exclusive scan
__global__ __launch_bounds__(256) void k_scan(const int* __restrict__ cnt_c, int* __restrict__ off_c, int* __restrict__ cur_c,
                                              const int* __restrict__ cnt_r, int* __restrict__ off_r, int* __restrict__ cur_r){
    const int n = (blockIdx.x==0) ? NF_ : N_;
    const int* cnt = (blockIdx.x==0) ? cnt_c : cnt_r;
    int* off = (blockIdx.x==0) ? off_c : off_r;
    int* cur = (blockIdx.x==0) ? cur_c : cur_r;
    __shared__ int part[256];
    int tid = threadIdx.x;
    int tpt = (n + 255) / 256;
    int i0 = tid * tpt;
    int s = 0;
    for (int i=0;i<tpt;++i){ int idx=i0+i; if (idx<n) s += cnt[idx]; }
    part[tid] = s;
    __syncthreads();
    if (tid == 0){
        int run = 0;
        for (int j=0;j<256;++j){ int t = part[j]; part[j] = run; run += t; }
        off[n] = run;
    }
    __syncthreads();
    int run = part[tid];
    for (int i=0;i<tpt;++i){
        int idx = i0+i;
        if (idx < n){ off[idx] = run; cur[idx] = run; run += cnt[idx]; }
    }
}

// ---------------------------------------------------------------- CSR build: fill edge lists
__global__ __launch_bounds__(256) void k_fill(const int* __restrict__ c_dst, const int* __restrict__ r_dst,
                                              int* __restrict__ cur_c, int* __restrict__ cur_r,
                                              int* __restrict__ eidx_c, int* __restrict__ eidx_r){
    int i = blockIdx.x*256 + threadIdx.x;
    if (i < EC_){
        int p = atomicAdd(&cur_c[c_dst[i]], 1);
        eidx_c[p] = i;
    } else if (i < EC_+ER_){
        int e = i - EC_;
        int p = atomicAdd(&cur_r[r_dst[e]], 1);
        eidx_r[p] = e;
    }
}

// ---------------------------------------------------------------- merged gather-aggregate (bf16), no atomics
__global__ __launch_bounds__(256) void k_gaggr2(const unsigned short* __restrict__ yc,
                                                const int* __restrict__ c_src,
                                                const int* __restrict__ eidx_c,
                                                const int* __restrict__ off_c,
                                                const float* __restrict__ mw_c,
                                                unsigned short* __restrict__ ac,
                                                const unsigned short* __restrict__ yr,
                                                const int* __restrict__ r_src,
                                                const int* __restrict__ eidx_r,
                                                const int* __restrict__ off_r,
                                                const float* __restrict__ mw_r,
                                                unsigned short* __restrict__ ar){
    int l = threadIdx.x & 63;
    const unsigned short* y; const int* src; const int* eidx; const int* off; const float* mw;
    unsigned short* aggr; int nseg, cpx, pb;
    if (blockIdx.x < 48000){
        pb = blockIdx.x; y = yc; src = c_src; eidx = eidx_c; off = off_c; mw = mw_c;
        aggr = ac; nseg = NF_; cpx = 6000;
    } else {
        pb = blockIdx.x - 48000; y = yr; src = r_src; eidx = eidx_r; off = off_r; mw = mw_r;
        aggr = ar; nseg = N_; cpx = 750;
    }
    int wg = (pb & 7)*cpx + (pb >> 3);          // XCD-chunked swizzle
    int idx = wg*4 + (threadIdx.x >> 6);        // g*nseg + d
    int g = idx / nseg, d = idx % nseg;
    int o0 = off[d], o1 = off[d+1];
    float acc = 0.f;
    for (int p=o0; p<o1; ++p){
        int e = eidx[p];
        acc += mw[e] * b2f(y[((size_t)g*nseg + src[e])*64 + l]);
    }
    aggr[(size_t)idx*64 + l] = f2b(acc);
}

// ---------------------------------------------------------------- weight prep: bf16 W^T panels (Q pre-scaled 0.25)
__global__ __launch_bounds__(256) void k_prepw(const float* __restrict__ Wqkv,
                                               const float* __restrict__ Wo,
                                               const float* __restrict__ W1,
                                               const float* __restrict__ W2,
                                               const float* __restrict__ csWlin,
                                               const float* __restrict__ rvWlin,
                                               const float* __restrict__ csWupd,
                                               const float* __restrict__ rvWupd,
                                               const float* __restrict__ fuW1,
                                               const float* __restrict__ fuW2,
                                               unsigned short* __restrict__ wt){
    int i = blockIdx.x*256 + threadIdx.x;
    if      (i < 12288){ int n=i>>6, k=i&63; float v = Wqkv[k*192+n]; if (n < 64) v *= 0.25f; wt[i] = f2b(v); }
    else if (i < 16384){ int z=i-12288; int n=z>>6, k=z&63; wt[i] = f2b(Wo[k*64+n]); }
    else if (i < 32768){ int z=i-16384; int n=z>>6, k=z&63; wt[i] = f2b(W1[k*256+n]); }
    else if (i < 49152){ int z=i-32768; int n=z>>8, k=z&255; wt[i] = f2b(W2[k*64+n]); }
    else if (i < 53248){ int z=i-49152; int n=z>>6, k=z&63; wt[i] = f2b(csWlin[k*64+n]); }
    else if (i < 57344){ int z=i-53248; int n=z>>6, k=z&63; wt[i] = f2b(rvWlin[k*64+n]); }
    else if (i < 65536){ int z=i-57344; int n=z>>7, k=z&127; wt[i] = f2b(csWupd[k*64+n]); }
    else if (i < 73728){ int z=i-65536; int n=z>>7, k=z&127; wt[i] = f2b(rvWupd[k*64+n]); }
    else if (i < 81920){ int z=i-73728; int n=z>>7, k=z&127; wt[i] = f2b(fuW1[k*64+n]); }
    else if (i < 86016){ int z=i-81920; int n=z>>6, k=z&63; wt[i] = f2b(fuW2[k*64+n]); }
}

// ---------------------------------------------------------------- merged node linear (causal + river[+ws-mean])
// bid < 3000: causal — gather x rows, also emit bf16 gathered rows (xg).
// bid >= 3000: river — compute ws mean inline, emit bf16 ws, then GEMM.
__global__ __launch_bounds__(256) void k_lin(const float* __restrict__ x,
                                             const unsigned short* __restrict__ wTc, const float* __restrict__ bc,
                                             const unsigned short* __restrict__ wTr, const float* __restrict__ br,
                                             unsigned short* __restrict__ yc, unsigned short* __restrict__ yr,
                                             unsigned short* __restrict__ xg, unsigned short* __restrict__ wsb){
    __shared__ unsigned short XBs[4][16*72];
    int w = threadIdx.x>>6, l = threadIdx.x&63;
    int lr = l&15, lg = l>>4;
    unsigned short* XB = XBs[w];
    const unsigned short* wT; const float* bias; unsigned short* y;
    int r0;
    if (blockIdx.x < 3000){
        r0 = (blockIdx.x*4 + w)*16;
        wT = wTc; bias = bc; y = yc;
        #pragma unroll
        for (int i=0;i<16;++i){
            int rr = r0+i;
            int g = rr/NF_, j = rr%NF_;
            int b = g/T_, t = g%T_, n = j/F_, f = j%F_;
            unsigned short us = f2b(x[((size_t)((b*N_+n)*F_+f)*T_ + t)*64 + l]);
            XB[i*72 + l] = us;
            xg[(size_t)rr*64 + l] = us;
        }
    } else {
        r0 = ((blockIdx.x-3000)*4 + w)*16;
        wT = wTr; bias = br; y = yr;
        #pragma unroll
        for (int i=0;i<16;++i){
            int rr = r0+i;              // g*N + n
            int g = rr/N_, n = rr%N_;
            int b = g/T_, t = g%T_;
            const float* base = x + ((size_t)(b*N_+n)*F_*T_ + t)*64 + l;
            float s = 0.f;
            #pragma unroll
            for (int f=0; f<F_; ++f) s += base[(size_t)f*T_*64];
            unsigned short us = f2b(s*(1.0f/F_));
            XB[i*72 + l] = us;
            wsb[(size_t)rr*64 + l] = us;
        }
    }
    LGKM0;
    bf16x8 a0 = *(const bf16x8*)&XB[lr*72 + lg*8];
    bf16x8 a1 = *(const bf16x8*)&XB[lr*72 + 32 + lg*8];
    f32x4 acc[4];
    #pragma unroll
    for (int ct=0;ct<4;++ct) acc[ct] = (f32x4){0.f,0.f,0.f,0.f};
    #pragma unroll
    for (int ct=0;ct<4;++ct){
        bf16x8 b0 = *(const bf16x8*)&wT[(ct*16+lr)*64 + lg*8];
        bf16x8 b1 = *(const bf16x8*)&wT[(ct*16+lr)*64 + 32 + lg*8];
        acc[ct] = __builtin_amdgcn_mfma_f32_16x16x32_bf16(a0, b0, acc[ct], 0,0,0);
        acc[ct] = __builtin_amdgcn_mfma_f32_16x16x32_bf16(a1, b1, acc[ct], 0,0,0);
    }
    #pragma unroll
    for (int ct=0;ct<4;++ct){
        float bv = bias[ct*16+lr];
        #pragma unroll
        for (int i=0;i<4;++i)
            y[(size_t)(r0+lg*4+i)*64 + ct*16+lr] = f2b(acc[ct][i] + bv);
    }
}

// ---------------------------------------------------------------- river update: u = relu([aggr|ws] @ Wu + b)  (all bf16)
__global__ __launch_bounds__(256) void k_upd16(const unsigned short* __restrict__ aggr,
                                               const unsigned short* __restrict__ xin,
                                               const unsigned short* __restrict__ wT,  // [64 n][128 k]
                                               const float* __restrict__ bu,
                                               unsigned short* __restrict__ u){
    __shared__ unsigned short XBs[4][16*136];
    int w = threadIdx.x>>6, l = threadIdx.x&63;
    int lr = l&15, lg = l>>4;
    unsigned short* XB = XBs[w];
    int r0 = (blockIdx.x*4 + w)*16;
    #pragma unroll
    for (int i=0;i<16;++i){
        int rr = r0+i;
        XB[i*136 + l]      = aggr[(size_t)rr*64 + l];
        XB[i*136 + 64 + l] = xin[(size_t)rr*64 + l];
    }
    LGKM0;
    bf16x8 a[4];
    #pragma unroll
    for (int kk=0;kk<4;++kk) a[kk] = *(const bf16x8*)&XB[lr*136 + kk*32 + lg*8];
    f32x4 acc[4];
    #pragma unroll
    for (int ct=0;ct<4;++ct) acc[ct] = (f32x4){0.f,0.f,0.f,0.f};
    #pragma unroll
    for (int ct=0;ct<4;++ct){
        #pragma unroll
        for (int kk=0;kk<4;++kk){
            bf16x8 b0 = *(const bf16x8*)&wT[(ct*16+lr)*128 + kk*32 + lg*8];
            acc[ct] = __builtin_amdgcn_mfma_f32_16x16x32_bf16(a[kk], b0, acc[ct], 0,0,0);
        }
    }
    #pragma unroll
    for (int ct=0;ct<4;++ct){
        float bv = bu[ct*16+lr];
        #pragma unroll
        for (int i=0;i<4;++i)
            u[(size_t)(r0+lg*4+i)*64 + ct*16+lr] = f2b(fmaxf(acc[ct][i] + bv, 0.f));
    }
}

// ---------------------------------------------------------------- fused causal-update + fusion MLP (all bf16, xg linear)
__global__ __launch_bounds__(256) void k_updfus(const unsigned short* __restrict__ aggr,
                                                const unsigned short* __restrict__ xg,
                                                const unsigned short* __restrict__ wuT,  // [64][128]
                                                const float* __restrict__ bu,
                                                const unsigned short* __restrict__ wsu,
                                                const unsigned short* __restrict__ w1T,  // [64][128]
                                                const float* __restrict__ b1,
                                                const unsigned short* __restrict__ w2T,  // [64][64]
                                                const float* __restrict__ b2,
                                                unsigned short* __restrict__ fused){
    __shared__ unsigned short XBs[4][16*136];
    __shared__ unsigned short X2s[4][16*136];
    int w = threadIdx.x>>6, l = threadIdx.x&63;
    int lr = l&15, lg = l>>4;
    unsigned short* XB = XBs[w];
    unsigned short* X2 = X2s[w];
    int r0 = (blockIdx.x*4 + w)*16;
    #pragma unroll
    for (int i=0;i<16;++i){
        int rr = r0+i;
        int g = rr/NF_, n = (rr%NF_)/F_;
        XB[i*136 + l]      = aggr[(size_t)rr*64 + l];
        XB[i*136 + 64 + l] = xg[(size_t)rr*64 + l];
        X2[i*136 + 64 + l] = wsu[((size_t)g*N_ + n)*64 + l];
    }
    LGKM0;
    {
        bf16x8 a[4];
        #pragma unroll
        for (int kk=0;kk<4;++kk) a[kk] = *(const bf16x8*)&XB[lr*136 + kk*32 + lg*8];
        f32x4 acc[4];
        #pragma unroll
        for (int ct=0;ct<4;++ct) acc[ct] = (f32x4){0.f,0.f,0.f,0.f};
        #pragma unroll
        for (int ct=0;ct<4;++ct){
            #pragma unroll
            for (int kk=0;kk<4;++kk){
                bf16x8 b0 = *(const bf16x8*)&wuT[(ct*16+lr)*128 + kk*32 + lg*8];
                acc[ct] = __builtin_amdgcn_mfma_f32_16x16x32_bf16(a[kk], b0, acc[ct], 0,0,0);
            }
        }
        #pragma unroll
        for (int ct=0;ct<4;++ct){
            float bv = bu[ct*16+lr];
            #pragma unroll
            for (int i=0;i<4;++i)
                X2[(lg*4+i)*136 + ct*16+lr] = f2b(fmaxf(acc[ct][i] + bv, 0.f));
        }
    }
    LGKM0;
    {
        bf16x8 a[4];
        #pragma unroll
        for (int kk=0;kk<4;++kk) a[kk] = *(const bf16x8*)&X2[lr*136 + kk*32 + lg*8];
        f32x4 acc[4];
        #pragma unroll
        for (int ct=0;ct<4;++ct) acc[ct] = (f32x4){0.f,0.f,0.f,0.f};
        #pragma unroll
        for (int ct=0;ct<4;++ct){
            #pragma unroll
            for (int kk=0;kk<4;++kk){
                bf16x8 b0 = *(const bf16x8*)&w1T[(ct*16+lr)*128 + kk*32 + lg*8];
                acc[ct] = __builtin_amdgcn_mfma_f32_16x16x32_bf16(a[kk], b0, acc[ct], 0,0,0);
            }
        }
        #pragma unroll
        for (int ct=0;ct<4;++ct){
            float bv = b1[ct*16+lr];
            #pragma unroll
            for (int i=0;i<4;++i)
                XB[(lg*4+i)*136 + ct*16+lr] = f2b(fmaxf(acc[ct][i] + bv, 0.f));
        }
    }
    LGKM0;
    {
        bf16x8 h0 = *(const bf16x8*)&XB[lr*136 + lg*8];
        bf16x8 h1 = *(const bf16x8*)&XB[lr*136 + 32 + lg*8];
        f32x4 acc[4];
        #pragma unroll
        for (int ct=0;ct<4;++ct) acc[ct] = (f32x4){0.f,0.f,0.f,0.f};
        #pragma unroll
        for (int ct=0;ct<4;++ct){
            bf16x8 b0 = *(const bf16x8*)&w2T[(ct*16+lr)*64 + lg*8];
            bf16x8 b1v= *(const bf16x8*)&w2T[(ct*16+lr)*64 + 32 + lg*8];
            acc[ct] = __builtin_amdgcn_mfma_f32_16x16x32_bf16(h0, b0, acc[ct], 0,0,0);
            acc[ct] = __builtin_amdgcn_mfma_f32_16x16x32_bf16(h1, b1v, acc[ct], 0,0,0);
        }
        #pragma unroll
        for (int ct=0;ct<4;++ct){
            float bv = b2[ct*16+lr];
            #pragma unroll
            for (int i=0;i<4;++i)
                fused[(size_t)(r0+lg*4+i)*64 + ct*16+lr] = f2b(acc[ct][i] + bv);
        }
    }
}

// ---------------------------------------------------------------- MFMA temporal transformer: 2 seqs per wave (ILP)
#define XSTR 72    // XB stride (shorts); LN-out / V^T / O staging
#define SSTR 136   // SC stride (shorts): Q 0-63, K 64-127; aliased as HID

__global__ __launch_bounds__(256) void k_xformer(
    const unsigned short* __restrict__ fused,
    const unsigned short* __restrict__ wtq,   // [192][64], Q-part pre-scaled 0.25
    const unsigned short* __restrict__ wto,   // [64][64]
    const unsigned short* __restrict__ wt1,   // [256][64]
    const unsigned short* __restrict__ wt2,   // [64][256]
    const float* __restrict__ bqkv, const float* __restrict__ bo,
    const float* __restrict__ fb1,  const float* __restrict__ fb2,
    const float* __restrict__ ln1g, const float* __restrict__ ln1b,
    const float* __restrict__ ln2g, const float* __restrict__ ln2b,
    float* __restrict__ out)
{
    __shared__ unsigned short XBs[4][2][16*XSTR];
    __shared__ unsigned short SCs[4][2][16*SSTR];

    int w  = threadIdx.x >> 6;
    int l  = threadIdx.x & 63;
    int lr = l & 15;
    int lg = l >> 4;

    unsigned short* XBp[2] = { XBs[w][0], XBs[w][1] };
    unsigned short* SCp[2] = { SCs[w][0], SCs[w][1] };

    int gbase = (blockIdx.x*4 + w)*2;

    float res[2][4][4];
    #pragma unroll
    for (int sq=0;sq<2;++sq){
        int gs = gbase + sq;
        int bb = gs / NF_, j = gs % NF_;
        const unsigned short* fp = fused + ((size_t)bb*T_*NF_ + j)*64;
        #pragma unroll
        for (int nt=0;nt<4;++nt)
            #pragma unroll
            for (int i=0;i<4;++i){
                int t = lg*4+i;
                res[sq][nt][i] = (t < 12) ? b2f(fp[(size_t)t*NF_*64 + nt*16 + lr]) : 0.f;
            }
    }

    // LN1 -> XB (both seqs)
    #pragma unroll
    for (int sq=0;sq<2;++sq){
        float sm[4], sqr[4];
        #pragma unroll
        for (int i=0;i<4;++i){
            sm[i]  = res[sq][0][i]+res[sq][1][i]+res[sq][2][i]+res[sq][3][i];
            sqr[i] = res[sq][0][i]*res[sq][0][i]+res[sq][1][i]*res[sq][1][i]
                   + res[sq][2][i]*res[sq][2][i]+res[sq][3][i]*res[sq][3][i];
        }
        #pragma unroll
        for (int m=1;m<16;m<<=1){
            #pragma unroll
            for (int i=0;i<4;++i){
                sm[i]  += __shfl_xor(sm[i], m, 64);
                sqr[i] += __shfl_xor(sqr[i], m, 64);
            }
        }
        #pragma unroll
        for (int nt=0;nt<4;++nt){
            float gg = ln1g[nt*16+lr], oo = ln1b[nt*16+lr];
            #pragma unroll
            for (int i=0;i<4;++i){
                float mn = sm[i]*(1.0f/64.0f);
                float var = sqr[i]*(1.0f/64.0f) - mn*mn;
                float rs = rsqrtf(var + 1e-5f);
                XBp[sq][(lg*4+i)*XSTR + nt*16 + lr] = f2b((res[sq][nt][i]-mn)*rs*gg + oo);
            }
        }
    }
    LGKM0;

    // QKV GEMM: Q,K -> SC; V^T -> XB (shared weight frags for both seqs)
    {
        bf16x8 a0[2], a1[2];
        #pragma unroll
        for (int sq=0;sq<2;++sq){
            a0[sq] = *(const bf16x8*)&XBp[sq][lr*XSTR + 0*32 + lg*8];
            a1[sq] = *(const bf16x8*)&XBp[sq][lr*XSTR + 1*32 + lg*8];
        }
        LGKM0;   // a-frags in regs before V overwrites XB
        #pragma unroll
        for (int p=0;p<3;++p){
            f32x4 acc[2][4];
            #pragma unroll
            for (int sq=0;sq<2;++sq)
                #pragma unroll
                for (int c=0;c<4;++c) acc[sq][c] = (f32x4){0.f,0.f,0.f,0.f};
            #pragma unroll
            for (int c=0;c<4;++c){
                int ct = p*4 + c;
                bf16x8 b0 = *(const bf16x8*)&wtq[(ct*16+lr)*64 + 0*32 + lg*8];
                bf16x8 b1v= *(const bf16x8*)&wtq[(ct*16+lr)*64 + 1*32 + lg*8];
                #pragma unroll
                for (int sq=0;sq<2;++sq){
                    acc[sq][c] = __builtin_amdgcn_mfma_f32_16x16x32_bf16(a0[sq], b0, acc[sq][c], 0,0,0);
                    acc[sq][c] = __builtin_amdgcn_mfma_f32_16x16x32_bf16(a1[sq], b1v, acc[sq][c], 0,0,0);
                }
            }
            if (p < 2){
                #pragma unroll
                for (int c=0;c<4;++c){
                    int ct = p*4 + c;
                    float bv = bqkv[ct*16+lr];
                    if (p == 0) bv *= 0.25f;
                    #pragma unroll
                    for (int sq=0;sq<2;++sq)
                        #pragma unroll
                        for (int i=0;i<4;++i)
                            SCp[sq][(lg*4+i)*SSTR + p*64 + c*16 + lr] = f2b(acc[sq][i<0?0:i>3?3:i][c<0?0:c]  // placeholder avoided below
                            );
                }
            }
            // NOTE: the above placeholder is replaced by the real stores just after
            if (p < 2){
                #pragma unroll
                for (int c=0;c<4;++c){
                    int ct = p*4 + c;
                    float bv = bqkv[ct*16+lr];
                    if (p == 0) bv *= 0.25f;
                    #pragma unroll
                    for (int sq=0;sq<2;++sq)
                        #pragma unroll
                        for (int i=0;i<4;++i)
                            SCp[sq][(lg*4+i)*SSTR + p*64 + c*16 + lr] = f2b(acc[sq][c][i] + bv);
                }
            } else {
                #pragma unroll
                for (int c=0;c<4;++c){
                    float bv = bqkv[128 + c*16 + lr];
                    #pragma unroll
                    for (int sq=0;sq<2;++sq){
                        short4v vv;
                        #pragma unroll
                        for (int i=0;i<4;++i) vv[i] = (short)f2b(acc[sq][c][i] + bv);
                        *(short4v*)&XBp[sq][lr*XSTR + c*16 + lg*4] = vv;   // VT'[d=c*16+lr][t=lg*4..+3]
                    }
                }
            }
        }
    }
    LGKM0;

    // MFMA attention per head, both seqs: S^T = K·Q^T ; P^T ; O^T = V^T·P^T
    {
        const bf16x8 bz = (bf16x8){0,0,0,0,0,0,0,0};
        #pragma unroll
        for (int hd=0; hd<4; ++hd){
            #pragma unroll
            for (int sq=0;sq<2;++sq){
                bf16x8 ak = bz, bq = bz;
                if (lg < 2){
                    ak = *(const bf16x8*)&SCp[sq][lr*SSTR + 64 + hd*16 + lg*8];
                    bq = *(const bf16x8*)&SCp[sq][lr*SSTR +      hd*16 + lg*8];
                }
                f32x4 st = __builtin_amdgcn_mfma_f32_16x16x32_bf16(ak, bq, (f32x4){0.f,0.f,0.f,0.f}, 0,0,0);
                float s0=st[0], s1v=st[1], s2=st[2], s3=st[3];
                if (lg == 3){ s0=s1v=s2=s3=-1e30f; }
                float mx = fmaxf(fmaxf(s0,s1v), fmaxf(s2,s3));
                mx = fmaxf(mx, __shfl_xor(mx, 16, 64));
                mx = fmaxf(mx, __shfl_xor(mx, 32, 64));
                float p0 = __expf(s0-mx), p1 = __expf(s1v-mx), p2 = __expf(s2-mx), p3 = __expf(s3-mx);
                float den = p0+p1+p2+p3;
                den += __shfl_xor(den, 16, 64);
                den += __shfl_xor(den, 32, 64);
                float inv = __builtin_amdgcn_rcpf(den);
                float q0 = __shfl_down(p0, 16, 64), q1 = __shfl_down(p1, 16, 64);
                float q2 = __shfl_down(p2, 16, 64), q3 = __shfl_down(p3, 16, 64);
                bf16x8 pb;
                {
                    float lo0 = (lg==0)? p0 : (lg==1)? q0 : 0.f;
                    float lo1 = (lg==0)? p1 : (lg==1)? q1 : 0.f;
                    float lo2 = (lg==0)? p2 : (lg==1)? q2 : 0.f;
                    float lo3 = (lg==0)? p3 : (lg==1)? q3 : 0.f;
                    float hi0 = (lg==0)? q0 : 0.f;
                    float hi1 = (lg==0)? q1 : 0.f;
                    float hi2 = (lg==0)? q2 : 0.f;
                    float hi3 = (lg==0)? q3 : 0.f;
                    pb[0]=(short)f2b(lo0); pb[1]=(short)f2b(lo1); pb[2]=(short)f2b(lo2); pb[3]=(short)f2b(lo3);
                    pb[4]=(short)f2b(hi0); pb[5]=(short)f2b(hi1); pb[6]=(short)f2b(hi2); pb[7]=(short)f2b(hi3);
                }
                bf16x8 av = bz;
                if (lg < 2) av = *(const bf16x8*)&XBp[sq][lr*XSTR + hd*16 + lg*8];
                f32x4 ot = __builtin_amdgcn_mfma_f32_16x16x32_bf16(av, pb, (f32x4){0.f,0.f,0.f,0.f}, 0,0,0);
                short4v ow;
                #pragma unroll
                for (int i=0;i<4;++i) ow[i] = (short)f2b(ot[i]*inv);
                *(short4v*)&XBp[sq][lr*XSTR + hd*16 + lg*4] = ow;
            }
        }
    }
    LGKM0;

    // proj + residual -> s1 (shared weight frags)
    float s1[2][4][4];
    {
        bf16x8 a0[2], a1[2];
        #pragma unroll
        for (int sq=0;sq<2;++sq){
            a0[sq] = *(const bf16x8*)&XBp[sq][lr*XSTR + 0*32 + lg*8];
            a1[sq] = *(const bf16x8*)&XBp[sq][lr*XSTR + 1*32 + lg*8];
        }
        f32x4 pacc[2][4];
        #pragma unroll
        for (int sq=0;sq<2;++sq)
            #pragma unroll
            for (int ct=0;ct<4;++ct) pacc[sq][ct] = (f32x4){0.f,0.f,0.f,0.f};
        #pragma unroll
        for (int ct=0;ct<4;++ct){
            bf16x8 b0 = *(const bf16x8*)&wto[(ct*16+lr)*64 + 0*32 + lg*8];
            bf16x8 b1v= *(const bf16x8*)&wto[(ct*16+lr)*64 + 1*32 + lg*8];
            #pragma unroll
            for (int sq=0;sq<2;++sq){
                pacc[sq][ct] = __builtin_amdgcn_mfma_f32_16x16x32_bf16(a0[sq], b0, pacc[sq][ct], 0,0,0);
                pacc[sq][ct] = __builtin_amdgcn_mfma_f32_16x16x32_bf16(a1[sq], b1v, pacc[sq][ct], 0,0,0);
            }
        }
        #pragma unroll
        for (int sq=0;sq<2;++sq)
            #pragma unroll
            for (int ct=0;ct<4;++ct){
                float bv = bo[ct*16+lr];
                #pragma unroll
                for (int i=0;i<4;++i)
                    s1[sq][ct][i] = res[sq][ct][i] + pacc[sq][ct][i] + bv;
            }
    }

    // LN2 -> XB (both seqs)
    #pragma unroll
    for (int sq=0;sq<2;++sq){
        float sm[4], sqr[4];
        #pragma unroll
        for (int i=0;i<4;++i){
            sm[i]  = s1[sq][0][i]+s1[sq][1][i]+s1[sq][2][i]+s1[sq][3][i];
            sqr[i] = s1[sq][0][i]*s1[sq][0][i]+s1[sq][1][i]*s1[sq][1][i]
                   + s1[sq][2][i]*s1[sq][2][i]+s1[sq][3][i]*s1[sq][3][i];
        }
        #pragma unroll
        for (int m=1;m<16;m<<=1){
            #pragma unroll
            for (int i=0;i<4;++i){
                sm[i]  += __shfl_xor(sm[i], m, 64);
                sqr[i] += __shfl_xor(sqr[i], m, 64);
            }
        }
        #pragma unroll
        for (int nt=0;nt<4;++nt){
            float gg = ln2g[nt*16+lr], oo = ln2b[nt*16+lr];
            #pragma unroll
            for (int i=0;i<4;++i){
                float mn = sm[i]*(1.0f/64.0f);
                float var = sqr[i]*(1.0f/64.0f) - mn*mn;
                float rs = rsqrtf(var + 1e-5f);
                XBp[sq][(lg*4+i)*XSTR + nt*16 + lr] = f2b((s1[sq][nt][i]-mn)*rs*gg + oo);
            }
        }
    }
    LGKM0;

    // FFN: two 128-wide halves; gelu via x*sigmoid; shared weight frags
    f32x4 oacc[2][4];
    #pragma unroll
    for (int sq=0;sq<2;++sq)
        #pragma unroll
        for (int ct=0;ct<4;++ct) oacc[sq][ct] = (f32x4){0.f,0.f,0.f,0.f};
    {
        bf16x8 a0[2], a1[2];
        #pragma unroll
        for (int sq=0;sq<2;++sq){
            a0[sq] = *(const bf16x8*)&XBp[sq][lr*XSTR + 0*32 + lg*8];
            a1[sq] = *(const bf16x8*)&XBp[sq][lr*XSTR + 1*32 + lg*8];
        }
        #pragma unroll
        for (int half=0; half<2; ++half){
            LGKM0;   // HID region reuse guard
            #pragma unroll
            for (int q=0; q<2; ++q){
                f32x4 facc[2][4];
                #pragma unroll
                for (int sq=0;sq<2;++sq)
                    #pragma unroll
                    for (int c=0;c<4;++c) facc[sq][c] = (f32x4){0.f,0.f,0.f,0.f};
                #pragma unroll
                for (int c=0;c<4;++c){
                    int ct = half*8 + q*4 + c;
                    bf16x8 b0 = *(const bf16x8*)&wt1[(ct*16+lr)*64 + 0*32 + lg*8];
                    bf16x8 b1v= *(const bf16x8*)&wt1[(ct*16+lr)*64 + 1*32 + lg*8];
                    #pragma unroll
                    for (int sq=0;sq<2;++sq){
                        facc[sq][c] = __builtin_amdgcn_mfma_f32_16x16x32_bf16(a0[sq], b0, facc[sq][c], 0,0,0);
                        facc[sq][c] = __builtin_amdgcn_mfma_f32_16x16x32_bf16(a1[sq], b1v, facc[sq][c], 0,0,0);
                    }
                }
                #pragma unroll
                for (int c=0;c<4;++c){
                    int ct = half*8 + q*4 + c;
                    float bv = fb1[ct*16+lr];
                    #pragma unroll
                    for (int sq=0;sq<2;++sq)
                        #pragma unroll
                        for (int i=0;i<4;++i){
                            float xv = facc[sq][c][i] + bv;
                            float x2 = xv*xv;
                            float z  = xv*(1.5957691216f + 0.0713548162f*x2);
                            float ez = __expf(-z);
                            SCp[sq][(lg*4+i)*SSTR + (q*4+c)*16 + lr] = f2b(xv * __builtin_amdgcn_rcpf(1.0f + ez));
                        }
                }
            }
            LGKM0;
            #pragma unroll
            for (int ks=0;ks<4;++ks){
                bf16x8 af[2];
                #pragma unroll
                for (int sq=0;sq<2;++sq)
                    af[sq] = *(const bf16x8*)&SCp[sq][lr*SSTR + ks*32 + lg*8];
                #pragma unroll
                for (int ct=0;ct<4;++ct){
                    bf16x8 bfr = *(const bf16x8*)&wt2[(ct*16+lr)*256 + half*128 + ks*32 + lg*8];
                    #pragma unroll
                    for (int sq=0;sq<2;++sq)
                        oacc[sq][ct] = __builtin_amdgcn_mfma_f32_16x16x32_bf16(af[sq], bfr, oacc[sq][ct], 0,0,0);
                }
            }
        }
    }

    // residual + mean over t (both seqs)
    #pragma unroll
    for (int sq=0;sq<2;++sq)
        #pragma unroll
        for (int ct=0;ct<4;++ct){
            float bv = fb2[ct*16+lr];
            float part = 0.f;
            #pragma unroll
            for (int i=0;i<4;++i){
                if (lg*4+i < 12) part += s1[sq][ct][i] + oacc[sq][ct][i] + bv;
            }
            part += __shfl_xor(part, 16, 64);
            part += __shfl_xor(part, 32, 64);
            if (lg == 0) out[(size_t)(gbase+sq)*64 + ct*16 + lr] = part*(1.0f/12.0f);
        }
}

// ----------------------------------------------------------------
extern "C" void kernel_launch(void* const* d_in, const int* in_sizes, int n_in,
                              void* d_out, int out_size, void* d_ws, size_t ws_size,
                              hipStream_t stream) {
    const float* x      = (const float*)d_in[0];
    const int*   r_ei   = (const int*)  d_in[1];
    const float* r_ea   = (const float*)d_in[2];
    const int*   c_ei   = (const int*)  d_in[3];
    const float* c_ew   = (const float*)d_in[4];
    const float* rvWlin = (const float*)d_in[5];
    const float* rvblin = (const float*)d_in[6];
    const float* rvWupd = (const float*)d_in[7];
    const float* rvbupd = (const float*)d_in[8];
    const float* rvgate = (const float*)d_in[9];
    const float* rvlw   = (const float*)d_in[10];
    const float* csWlin = (const float*)d_in[11];
    const float* csblin = (const float*)d_in[12];
    const float* csWupd = (const float*)d_in[13];
    const float* csbupd = (const float*)d_in[14];
    const float* csgate = (const float*)d_in[15];
    const float* cslw   = (const float*)d_in[16];
    const float* fuW1   = (const float*)d_in[17];
    const float* fub1   = (const float*)d_in[18];
    const float* fuW2   = (const float*)d_in[19];
    const float* fub2   = (const float*)d_in[20];
    const float* ln1g   = (const float*)d_in[21];
    const float* ln1b   = (const float*)d_in[22];
    const float* ln2g   = (const float*)d_in[23];
    const float* ln2b   = (const float*)d_in[24];
    const float* Wqkv   = (const float*)d_in[25];
    const float* bqkv   = (const float*)d_in[26];
    const float* Wo     = (const float*)d_in[27];
    const float* bo     = (const float*)d_in[28];
    const float* ffW1   = (const float*)d_in[29];
    const float* ffb1   = (const float*)d_in[30];
    const float* ffW2   = (const float*)d_in[31];
    const float* ffb2   = (const float*)d_in[32];

    float* wsp  = (float*)d_ws;
    unsigned short* FNY_b = (unsigned short*)wsp;                    // causal y bf16, then FUSED bf16
    unsigned short* FNA_b = (unsigned short*)(wsp + 12288000);       // causal aggr bf16 (first half of region)
    unsigned short* XG_b  = (unsigned short*)(wsp + 12288000 + 6144000); // gathered x bf16 (second half)
    unsigned short* WS_b  = (unsigned short*)(wsp + 24576000);       // watershed mean bf16
    unsigned short* WSY_b = (unsigned short*)(wsp + 26112000);       // river y bf16
    unsigned short* WSA_b = (unsigned short*)(wsp + 27648000);       // river aggr bf16
    float* WSU  = wsp + 29184000;                                    // CSR scratch, then river u bf16
    unsigned short* WSU_b = (unsigned short*)WSU;
    unsigned short* wt = (unsigned short*)(wsp + 30720000);
    float* outp = (float*)d_out;

    int* ibase  = (int*)WSU;
    int* cnt_c  = ibase;
    int* cnt_r  = ibase + 8000;
    int* off_c  = ibase + 9000;
    int* off_r  = ibase + 17001;
    int* cur_c  = ibase + 18002;
    int* cur_r  = ibase + 26002;
    int* eidx_c = ibase + 27002;
    int* eidx_r = ibase + 51002;
    float* mw_c = (float*)(ibase + 53002);
    float* mw_r = (float*)(ibase + 77002);

    const int* c_src = c_ei;
    const int* c_dst = c_ei + EC_;
    const int* r_src = r_ei;
    const int* r_dst = r_ei + ER_;

    hipMemsetAsync(cnt_c, 0, 9000*sizeof(int), stream);

    k_prepw<<<336, 256, 0, stream>>>(Wqkv, Wo, ffW1, ffW2, csWlin, rvWlin, csWupd, rvWupd,
                                     fuW1, fuW2, wt);
    k_mwhist<<<(EC_+ER_+255)/256, 256, 0, stream>>>(c_dst, r_dst, c_ew, cslw, csgate,
                                                    r_ea, rvlw, rvgate, mw_c, mw_r, cnt_c, cnt_r);
    k_scan<<<2, 256, 0, stream>>>(cnt_c, off_c, cur_c, cnt_r, off_r, cur_r);
    k_fill<<<(EC_+ER_+255)/256, 256, 0, stream>>>(c_dst, r_dst, cur_c, cur_r, eidx_c, eidx_r);

    // merged node linear (causal gather + xg emit; river ws-mean + wsb emit)
    k_lin<<<3375, 256, 0, stream>>>(x, wt+49152, csblin, wt+53248, rvblin,
                                    FNY_b, WSY_b, XG_b, WS_b);

    // merged gather-aggregation (no atomics)
    k_gaggr2<<<54000, 256, 0, stream>>>(FNY_b, c_src, eidx_c, off_c, mw_c, FNA_b,
                                        WSY_b, r_src, eidx_r, off_r, mw_r, WSA_b);

    // river update (clobbers CSR scratch -> OK, consumers done)
    k_upd16<<<375, 256, 0, stream>>>(WSA_b, WS_b, wt+65536, rvbupd, WSU_b);

    // fused causal update + fusion MLP -> FUSED bf16 (into FNY region)
    k_updfus<<<3000, 256, 0, stream>>>(FNA_b, XG_b, wt+57344, csbupd, WSU_b,
                                       wt+73728, fub1, wt+81920, fub2, FNY_b);

    // 2-seq-per-wave MFMA transformer
    k_xformer<<<2000, 256, 0, stream>>>(FNY_b,
                                        wt, wt+12288, wt+16384, wt+32768,
                                        bqkv, bo, ffb1, ffb2,
                                        ln1g, ln1b, ln2g, ln2b,
                                        outp);
}

// Round 11
// 361.748 us; speedup vs baseline: 1.2099x; 1.0024x over previous
//
#include <hip/hip_runtime.h>
#include <math.h>

#define B_ 2
#define N_ 1000
#define F_ 8
#define T_ 12
#define H_ 64
#define G_ 24      // B*T
#define NF_ 8000   // N*F
#define ER_ 2000
#define EC_ 24000

typedef short bf16x8 __attribute__((ext_vector_type(8)));
typedef short short4v __attribute__((ext_vector_type(4)));
typedef float f32x4 __attribute__((ext_vector_type(4)));

#define LGKM0 do { asm volatile("s_waitcnt lgkmcnt(0)" ::: "memory"); __builtin_amdgcn_sched_barrier(0); } while(0)

__device__ __forceinline__ float sigf(float x){ return 1.0f/(1.0f+__expf(-x)); }

// f32 -> bf16 (RNE)
__device__ __forceinline__ unsigned short f2b(float f){
    unsigned u = __float_as_uint(f);
    unsigned r = (u + 0x7FFFu + ((u >> 16) & 1u)) >> 16;
    return (unsigned short)r;
}
__device__ __forceinline__ float b2f(unsigned short u){
    return __uint_as_float(((unsigned)u) << 16);
}

// ---------------------------------------------------------------- CSR build: mw + histogram
__global__ __launch_bounds__(256) void k_mwhist(const int* __restrict__ c_dst, const int* __restrict__ r_dst,
                                                const float* __restrict__ c_ew, const float* __restrict__ c_lw,
                                                const float* __restrict__ c_gate,
                                                const float* __restrict__ r_ew, const float* __restrict__ r_lw,
                                                const float* __restrict__ r_gate,
                                                float* __restrict__ mw_c, float* __restrict__ mw_r,
                                                int* __restrict__ cnt_c, int* __restrict__ cnt_r){
    int i = blockIdx.x*256 + threadIdx.x;
    if (i < EC_){
        float gs = sigf(c_gate[0]);
        mw_c[i] = gs*c_ew[i] + (1.f-gs)*sigf(c_lw[i]);
        atomicAdd(&cnt_c[c_dst[i]], 1);
    } else if (i < EC_+ER_){
        int e = i - EC_;
        float gs = sigf(r_gate[0]);
        mw_r[e] = gs*r_ew[e] + (1.f-gs)*sigf(r_lw[e]);
        atomicAdd(&cnt_r[r_dst[e]], 1);
    }
}

// ---------------------------------------------------------------- CSR build: exclusive scan
__global__ __launch_bounds__(256) void k_scan(const int* __restrict__ cnt_c, int* __restrict__ off_c, int* __restrict__ cur_c,
                                              const int* __restrict__ cnt_r, int* __restrict__ off_r, int* __restrict__ cur_r){
    const int n = (blockIdx.x==0) ? NF_ : N_;
    const int* cnt = (blockIdx.x==0) ? cnt_c : cnt_r;
    int* off = (blockIdx.x==0) ? off_c : off_r;
    int* cur = (blockIdx.x==0) ? cur_c : cur_r;
    __shared__ int part[256];
    int tid = threadIdx.x;
    int tpt = (n + 255) / 256;
    int i0 = tid * tpt;
    int s = 0;
    for (int i=0;i<tpt;++i){ int idx=i0+i; if (idx<n) s += cnt[idx]; }
    part[tid] = s;
    __syncthreads();
    if (tid == 0){
        int run = 0;
        for (int j=0;j<256;++j){ int t = part[j]; part[j] = run; run += t; }
        off[n] = run;
    }
    __syncthreads();
    int run = part[tid];
    for (int i=0;i<tpt;++i){
        int idx = i0+i;
        if (idx < n){ off[idx] = run; cur[idx] = run; run += cnt[idx]; }
    }
}

// ---------------------------------------------------------------- CSR build: fill edge lists
__global__ __launch_bounds__(256) void k_fill(const int* __restrict__ c_dst, const int* __restrict__ r_dst,
                                              int* __restrict__ cur_c, int* __restrict__ cur_r,
                                              int* __restrict__ eidx_c, int* __restrict__ eidx_r){
    int i = blockIdx.x*256 + threadIdx.x;
    if (i < EC_){
        int p = atomicAdd(&cur_c[c_dst[i]], 1);
        eidx_c[p] = i;
    } else if (i < EC_+ER_){
        int e = i - EC_;
        int p = atomicAdd(&cur_r[r_dst[e]], 1);
        eidx_r[p] = e;
    }
}

// ---------------------------------------------------------------- merged gather-aggregate (bf16), no atomics
__global__ __launch_bounds__(256) void k_gaggr2(const unsigned short* __restrict__ yc,
                                                const int* __restrict__ c_src,
                                                const int* __restrict__ eidx_c,
                                                const int* __restrict__ off_c,
                                                const float* __restrict__ mw_c,
                                                unsigned short* __restrict__ ac,
                                                const unsigned short* __restrict__ yr,
                                                const int* __restrict__ r_src,
                                                const int* __restrict__ eidx_r,
                                                const int* __restrict__ off_r,
                                                const float* __restrict__ mw_r,
                                                unsigned short* __restrict__ ar){
    int l = threadIdx.x & 63;
    const unsigned short* y; const int* src; const int* eidx; const int* off; const float* mw;
    unsigned short* aggr; int nseg, cpx, pb;
    if (blockIdx.x < 48000){
        pb = blockIdx.x; y = yc; src = c_src; eidx = eidx_c; off = off_c; mw = mw_c;
        aggr = ac; nseg = NF_; cpx = 6000;
    } else {
        pb = blockIdx.x - 48000; y = yr; src = r_src; eidx = eidx_r; off = off_r; mw = mw_r;
        aggr = ar; nseg = N_; cpx = 750;
    }
    int wg = (pb & 7)*cpx + (pb >> 3);          // XCD-chunked swizzle
    int idx = wg*4 + (threadIdx.x >> 6);        // g*nseg + d
    int g = idx / nseg, d = idx % nseg;
    int o0 = off[d], o1 = off[d+1];
    float acc = 0.f;
    for (int p=o0; p<o1; ++p){
        int e = eidx[p];
        acc += mw[e] * b2f(y[((size_t)g*nseg + src[e])*64 + l]);
    }
    aggr[(size_t)idx*64 + l] = f2b(acc);
}

// ---------------------------------------------------------------- weight prep: bf16 W^T panels (Q pre-scaled 0.25)
__global__ __launch_bounds__(256) void k_prepw(const float* __restrict__ Wqkv,
                                               const float* __restrict__ Wo,
                                               const float* __restrict__ W1,
                                               const float* __restrict__ W2,
                                               const float* __restrict__ csWlin,
                                               const float* __restrict__ rvWlin,
                                               const float* __restrict__ csWupd,
                                               const float* __restrict__ rvWupd,
                                               const float* __restrict__ fuW1,
                                               const float* __restrict__ fuW2,
                                               unsigned short* __restrict__ wt){
    int i = blockIdx.x*256 + threadIdx.x;
    if      (i < 12288){ int n=i>>6, k=i&63; float v = Wqkv[k*192+n]; if (n < 64) v *= 0.25f; wt[i] = f2b(v); }
    else if (i < 16384){ int z=i-12288; int n=z>>6, k=z&63; wt[i] = f2b(Wo[k*64+n]); }
    else if (i < 32768){ int z=i-16384; int n=z>>6, k=z&63; wt[i] = f2b(W1[k*256+n]); }
    else if (i < 49152){ int z=i-32768; int n=z>>8, k=z&255; wt[i] = f2b(W2[k*64+n]); }
    else if (i < 53248){ int z=i-49152; int n=z>>6, k=z&63; wt[i] = f2b(csWlin[k*64+n]); }
    else if (i < 57344){ int z=i-53248; int n=z>>6, k=z&63; wt[i] = f2b(rvWlin[k*64+n]); }
    else if (i < 65536){ int z=i-57344; int n=z>>7, k=z&127; wt[i] = f2b(csWupd[k*64+n]); }
    else if (i < 73728){ int z=i-65536; int n=z>>7, k=z&127; wt[i] = f2b(rvWupd[k*64+n]); }
    else if (i < 81920){ int z=i-73728; int n=z>>7, k=z&127; wt[i] = f2b(fuW1[k*64+n]); }
    else if (i < 86016){ int z=i-81920; int n=z>>6, k=z&63; wt[i] = f2b(fuW2[k*64+n]); }
}

// ---------------------------------------------------------------- single-pass node linear:
// block = 64 causal rows (8 n x 8 f of one g). Emits: causal y, xg, ws-mean (bf16) and river y
// (wave 0 does the block's 8-row river GEMM from the staged f-means).
__global__ __launch_bounds__(256) void k_lin(const float* __restrict__ x,
                                             const unsigned short* __restrict__ wTc, const float* __restrict__ bc,
                                             const unsigned short* __restrict__ wTr, const float* __restrict__ br,
                                             unsigned short* __restrict__ yc, unsigned short* __restrict__ yr,
                                             unsigned short* __restrict__ xg, unsigned short* __restrict__ wsb){
    __shared__ unsigned short XBs[4][16*72];
    __shared__ unsigned short WST[16*72];     // rows 0..7 valid (block's 8 f-means)
    int w = threadIdx.x>>6, l = threadIdx.x&63;
    int lr = l&15, lg = l>>4;
    unsigned short* XB = XBs[w];
    int r0 = (blockIdx.x*4 + w)*16;           // NF_=8000, 8000%64==0 per block? 8000/64=125 exact -> no g straddle
    int g  = r0/NF_;
    int j0 = r0%NF_;
    float fsum0 = 0.f, fsum1 = 0.f;
    #pragma unroll
    for (int i=0;i<16;++i){
        int rr = r0+i;
        int j = j0+i;
        int b = g/T_, t = g%T_, n = j/F_, f = j%F_;
        float v = x[((size_t)((b*N_+n)*F_+f)*T_ + t)*64 + l];
        unsigned short us = f2b(v);
        XB[i*72 + l] = us;
        xg[(size_t)rr*64 + l] = us;
        if (i < 8) fsum0 += v; else fsum1 += v;
    }
    // ws rows: wave w holds n-locals w*2, w*2+1
    {
        int nb = j0/F_;                        // wave's first n (global within g)
        unsigned short u0 = f2b(fsum0*0.125f);
        unsigned short u1 = f2b(fsum1*0.125f);
        WST[(w*2+0)*72 + l] = u0;
        WST[(w*2+1)*72 + l] = u1;
        wsb[((size_t)g*N_ + nb    )*64 + l] = u0;
        wsb[((size_t)g*N_ + nb + 1)*64 + l] = u1;
    }
    __syncthreads();
    // causal GEMM (per wave)
    {
        bf16x8 a0 = *(const bf16x8*)&XB[lr*72 + lg*8];
        bf16x8 a1 = *(const bf16x8*)&XB[lr*72 + 32 + lg*8];
        f32x4 acc[4];
        #pragma unroll
        for (int ct=0;ct<4;++ct) acc[ct] = (f32x4){0.f,0.f,0.f,0.f};
        #pragma unroll
        for (int ct=0;ct<4;++ct){
            bf16x8 b0 = *(const bf16x8*)&wTc[(ct*16+lr)*64 + lg*8];
            bf16x8 b1 = *(const bf16x8*)&wTc[(ct*16+lr)*64 + 32 + lg*8];
            acc[ct] = __builtin_amdgcn_mfma_f32_16x16x32_bf16(a0, b0, acc[ct], 0,0,0);
            acc[ct] = __builtin_amdgcn_mfma_f32_16x16x32_bf16(a1, b1, acc[ct], 0,0,0);
        }
        #pragma unroll
        for (int ct=0;ct<4;++ct){
            float bv = bc[ct*16+lr];
            #pragma unroll
            for (int i=0;i<4;++i)
                yc[(size_t)(r0+lg*4+i)*64 + ct*16+lr] = f2b(acc[ct][i] + bv);
        }
    }
    // river GEMM for the block's 8 n-rows (wave 0 only; WST rows 8-15 garbage -> unstored)
    if (w == 0){
        int nb0 = ((blockIdx.x*64)%NF_)/F_;    // block's first n
        int gb  = (blockIdx.x*64)/NF_;
        bf16x8 a0 = *(const bf16x8*)&WST[lr*72 + lg*8];
        bf16x8 a1 = *(const bf16x8*)&WST[lr*72 + 32 + lg*8];
        f32x4 acc[4];
        #pragma unroll
        for (int ct=0;ct<4;++ct) acc[ct] = (f32x4){0.f,0.f,0.f,0.f};
        #pragma unroll
        for (int ct=0;ct<4;++ct){
            bf16x8 b0 = *(const bf16x8*)&wTr[(ct*16+lr)*64 + lg*8];
            bf16x8 b1 = *(const bf16x8*)&wTr[(ct*16+lr)*64 + 32 + lg*8];
            acc[ct] = __builtin_amdgcn_mfma_f32_16x16x32_bf16(a0, b0, acc[ct], 0,0,0);
            acc[ct] = __builtin_amdgcn_mfma_f32_16x16x32_bf16(a1, b1, acc[ct], 0,0,0);
        }
        if (lg < 2){   // rows 0..7 valid
            #pragma unroll
            for (int ct=0;ct<4;++ct){
                float bv = br[ct*16+lr];
                #pragma unroll
                for (int i=0;i<4;++i)
                    yr[((size_t)gb*N_ + nb0 + lg*4+i)*64 + ct*16+lr] = f2b(acc[ct][i] + bv);
            }
        }
    }
}

// ---------------------------------------------------------------- river update: u = relu([aggr|ws] @ Wu + b)  (all bf16)
__global__ __launch_bounds__(256) void k_upd16(const unsigned short* __restrict__ aggr,
                                               const unsigned short* __restrict__ xin,
                                               const unsigned short* __restrict__ wT,  // [64 n][128 k]
                                               const float* __restrict__ bu,
                                               unsigned short* __restrict__ u){
    __shared__ unsigned short XBs[4][16*136];
    int w = threadIdx.x>>6, l = threadIdx.x&63;
    int lr = l&15, lg = l>>4;
    unsigned short* XB = XBs[w];
    int r0 = (blockIdx.x*4 + w)*16;
    #pragma unroll
    for (int i=0;i<16;++i){
        int rr = r0+i;
        XB[i*136 + l]      = aggr[(size_t)rr*64 + l];
        XB[i*136 + 64 + l] = xin[(size_t)rr*64 + l];
    }
    LGKM0;
    bf16x8 a[4];
    #pragma unroll
    for (int kk=0;kk<4;++kk) a[kk] = *(const bf16x8*)&XB[lr*136 + kk*32 + lg*8];
    f32x4 acc[4];
    #pragma unroll
    for (int ct=0;ct<4;++ct) acc[ct] = (f32x4){0.f,0.f,0.f,0.f};
    #pragma unroll
    for (int ct=0;ct<4;++ct){
        #pragma unroll
        for (int kk=0;kk<4;++kk){
            bf16x8 b0 = *(const bf16x8*)&wT[(ct*16+lr)*128 + kk*32 + lg*8];
            acc[ct] = __builtin_amdgcn_mfma_f32_16x16x32_bf16(a[kk], b0, acc[ct], 0,0,0);
        }
    }
    #pragma unroll
    for (int ct=0;ct<4;++ct){
        float bv = bu[ct*16+lr];
        #pragma unroll
        for (int i=0;i<4;++i)
            u[(size_t)(r0+lg*4+i)*64 + ct*16+lr] = f2b(fmaxf(acc[ct][i] + bv, 0.f));
    }
}

// ---------------------------------------------------------------- fused causal-update + fusion MLP (all bf16)
__global__ __launch_bounds__(256) void k_updfus(const unsigned short* __restrict__ aggr,
                                                const unsigned short* __restrict__ xg,
                                                const unsigned short* __restrict__ wuT,  // [64][128]
                                                const float* __restrict__ bu,
                                                const unsigned short* __restrict__ wsu,
                                                const unsigned short* __restrict__ w1T,  // [64][128]
                                                const float* __restrict__ b1,
                                                const unsigned short* __restrict__ w2T,  // [64][64]
                                                const float* __restrict__ b2,
                                                unsigned short* __restrict__ fused){
    __shared__ unsigned short XBs[4][16*136];
    __shared__ unsigned short X2s[4][16*136];
    int w = threadIdx.x>>6, l = threadIdx.x&63;
    int lr = l&15, lg = l>>4;
    unsigned short* XB = XBs[w];
    unsigned short* X2 = X2s[w];
    int r0 = (blockIdx.x*4 + w)*16;
    #pragma unroll
    for (int i=0;i<16;++i){
        int rr = r0+i;
        int g = rr/NF_, n = (rr%NF_)/F_;
        XB[i*136 + l]      = aggr[(size_t)rr*64 + l];
        XB[i*136 + 64 + l] = xg[(size_t)rr*64 + l];
        X2[i*136 + 64 + l] = wsu[((size_t)g*N_ + n)*64 + l];
    }
    LGKM0;
    {
        bf16x8 a[4];
        #pragma unroll
        for (int kk=0;kk<4;++kk) a[kk] = *(const bf16x8*)&XB[lr*136 + kk*32 + lg*8];
        f32x4 acc[4];
        #pragma unroll
        for (int ct=0;ct<4;++ct) acc[ct] = (f32x4){0.f,0.f,0.f,0.f};
        #pragma unroll
        for (int ct=0;ct<4;++ct){
            #pragma unroll
            for (int kk=0;kk<4;++kk){
                bf16x8 b0 = *(const bf16x8*)&wuT[(ct*16+lr)*128 + kk*32 + lg*8];
                acc[ct] = __builtin_amdgcn_mfma_f32_16x16x32_bf16(a[kk], b0, acc[ct], 0,0,0);
            }
        }
        #pragma unroll
        for (int ct=0;ct<4;++ct){
            float bv = bu[ct*16+lr];
            #pragma unroll
            for (int i=0;i<4;++i)
                X2[(lg*4+i)*136 + ct*16+lr] = f2b(fmaxf(acc[ct][i] + bv, 0.f));
        }
    }
    LGKM0;
    {
        bf16x8 a[4];
        #pragma unroll
        for (int kk=0;kk<4;++kk) a[kk] = *(const bf16x8*)&X2[lr*136 + kk*32 + lg*8];
        f32x4 acc[4];
        #pragma unroll
        for (int ct=0;ct<4;++ct) acc[ct] = (f32x4){0.f,0.f,0.f,0.f};
        #pragma unroll
        for (int ct=0;ct<4;++ct){
            #pragma unroll
            for (int kk=0;kk<4;++kk){
                bf16x8 b0 = *(const bf16x8*)&w1T[(ct*16+lr)*128 + kk*32 + lg*8];
                acc[ct] = __builtin_amdgcn_mfma_f32_16x16x32_bf16(a[kk], b0, acc[ct], 0,0,0);
            }
        }
        #pragma unroll
        for (int ct=0;ct<4;++ct){
            float bv = b1[ct*16+lr];
            #pragma unroll
            for (int i=0;i<4;++i)
                XB[(lg*4+i)*136 + ct*16+lr] = f2b(fmaxf(acc[ct][i] + bv, 0.f));
        }
    }
    LGKM0;
    {
        bf16x8 h0 = *(const bf16x8*)&XB[lr*136 + lg*8];
        bf16x8 h1 = *(const bf16x8*)&XB[lr*136 + 32 + lg*8];
        f32x4 acc[4];
        #pragma unroll
        for (int ct=0;ct<4;++ct) acc[ct] = (f32x4){0.f,0.f,0.f,0.f};
        #pragma unroll
        for (int ct=0;ct<4;++ct){
            bf16x8 b0 = *(const bf16x8*)&w2T[(ct*16+lr)*64 + lg*8];
            bf16x8 b1v= *(const bf16x8*)&w2T[(ct*16+lr)*64 + 32 + lg*8];
            acc[ct] = __builtin_amdgcn_mfma_f32_16x16x32_bf16(h0, b0, acc[ct], 0,0,0);
            acc[ct] = __builtin_amdgcn_mfma_f32_16x16x32_bf16(h1, b1v, acc[ct], 0,0,0);
        }
        #pragma unroll
        for (int ct=0;ct<4;++ct){
            float bv = b2[ct*16+lr];
            #pragma unroll
            for (int i=0;i<4;++i)
                fused[(size_t)(r0+lg*4+i)*64 + ct*16+lr] = f2b(acc[ct][i] + bv);
        }
    }
}

// ---------------------------------------------------------------- MFMA temporal transformer: 2 seqs/wave, 12-row SC
#define XSTR 72    // XB stride (shorts); LN-out / V^T / O staging (16 rows)
#define SSTR 136   // SC stride (shorts): Q 0-63, K 64-127; 12 rows/seq + tail pad; aliased as HID
#define SCSZ (12*SSTR)

__global__ __launch_bounds__(256) void k_xformer(
    const unsigned short* __restrict__ fused,
    const unsigned short* __restrict__ wtq,   // [192][64], Q-part pre-scaled 0.25
    const unsigned short* __restrict__ wto,   // [64][64]
    const unsigned short* __restrict__ wt1,   // [256][64]
    const unsigned short* __restrict__ wt2,   // [64][256]
    const float* __restrict__ bqkv, const float* __restrict__ bo,
    const float* __restrict__ fb1,  const float* __restrict__ fb2,
    const float* __restrict__ ln1g, const float* __restrict__ ln1b,
    const float* __restrict__ ln2g, const float* __restrict__ ln2b,
    float* __restrict__ out)
{
    __shared__ unsigned short XBs[4][2][16*XSTR];
    __shared__ unsigned short SCmem[8*SCSZ + 544];   // 12-row slices + tail pad for benign row-12..15 reads

    int w  = threadIdx.x >> 6;
    int l  = threadIdx.x & 63;
    int lr = l & 15;
    int lg = l >> 4;

    unsigned short* XBp[2] = { XBs[w][0], XBs[w][1] };
    unsigned short* SCp[2] = { &SCmem[(w*2+0)*SCSZ], &SCmem[(w*2+1)*SCSZ] };

    int gbase = (blockIdx.x*4 + w)*2;

    float res[2][4][4];
    #pragma unroll
    for (int sq=0;sq<2;++sq){
        int gs = gbase + sq;
        int bb = gs / NF_, j = gs % NF_;
        const unsigned short* fp = fused + ((size_t)bb*T_*NF_ + j)*64;
        #pragma unroll
        for (int nt=0;nt<4;++nt)
            #pragma unroll
            for (int i=0;i<4;++i){
                int t = lg*4+i;
                res[sq][nt][i] = (t < 12) ? b2f(fp[(size_t)t*NF_*64 + nt*16 + lr]) : 0.f;
            }
    }

    // LN1 -> XB (both seqs)
    #pragma unroll
    for (int sq=0;sq<2;++sq){
        float sm[4], sqr[4];
        #pragma unroll
        for (int i=0;i<4;++i){
            sm[i]  = res[sq][0][i]+res[sq][1][i]+res[sq][2][i]+res[sq][3][i];
            sqr[i] = res[sq][0][i]*res[sq][0][i]+res[sq][1][i]*res[sq][1][i]
                   + res[sq][2][i]*res[sq][2][i]+res[sq][3][i]*res[sq][3][i];
        }
        #pragma unroll
        for (int m=1;m<16;m<<=1){
            #pragma unroll
            for (int i=0;i<4;++i){
                sm[i]  += __shfl_xor(sm[i], m, 64);
                sqr[i] += __shfl_xor(sqr[i], m, 64);
            }
        }
        #pragma unroll
        for (int nt=0;nt<4;++nt){
            float gg = ln1g[nt*16+lr], oo = ln1b[nt*16+lr];
            #pragma unroll
            for (int i=0;i<4;++i){
                float mn = sm[i]*(1.0f/64.0f);
                float var = sqr[i]*(1.0f/64.0f) - mn*mn;
                float rs = rsqrtf(var + 1e-5f);
                XBp[sq][(lg*4+i)*XSTR + nt*16 + lr] = f2b((res[sq][nt][i]-mn)*rs*gg + oo);
            }
        }
    }
    LGKM0;

    // QKV GEMM: Q,K -> SC (rows<12 only); V^T -> XB (shared weight frags)
    {
        bf16x8 a0[2], a1[2];
        #pragma unroll
        for (int sq=0;sq<2;++sq){
            a0[sq] = *(const bf16x8*)&XBp[sq][lr*XSTR + 0*32 + lg*8];
            a1[sq] = *(const bf16x8*)&XBp[sq][lr*XSTR + 1*32 + lg*8];
        }
        LGKM0;   // a-frags in regs before V overwrites XB
        #pragma unroll
        for (int p=0;p<3;++p){
            f32x4 acc[2][4];
            #pragma unroll
            for (int sq=0;sq<2;++sq)
                #pragma unroll
                for (int c=0;c<4;++c) acc[sq][c] = (f32x4){0.f,0.f,0.f,0.f};
            #pragma unroll
            for (int c=0;c<4;++c){
                int ct = p*4 + c;
                bf16x8 b0 = *(const bf16x8*)&wtq[(ct*16+lr)*64 + 0*32 + lg*8];
                bf16x8 b1v= *(const bf16x8*)&wtq[(ct*16+lr)*64 + 1*32 + lg*8];
                #pragma unroll
                for (int sq=0;sq<2;++sq){
                    acc[sq][c] = __builtin_amdgcn_mfma_f32_16x16x32_bf16(a0[sq], b0, acc[sq][c], 0,0,0);
                    acc[sq][c] = __builtin_amdgcn_mfma_f32_16x16x32_bf16(a1[sq], b1v, acc[sq][c], 0,0,0);
                }
            }
            if (p < 2){
                #pragma unroll
                for (int c=0;c<4;++c){
                    int ct = p*4 + c;
                    float bv = bqkv[ct*16+lr];
                    if (p == 0) bv *= 0.25f;
                    if (lg < 3){    // rows lg*4+i < 12 only
                        #pragma unroll
                        for (int sq=0;sq<2;++sq)
                            #pragma unroll
                            for (int i=0;i<4;++i)
                                SCp[sq][(lg*4+i)*SSTR + p*64 + c*16 + lr] = f2b(acc[sq][c][i] + bv);
                    }
                }
            } else {
                #pragma unroll
                for (int c=0;c<4;++c){
                    float bv = bqkv[128 + c*16 + lr];
                    #pragma unroll
                    for (int sq=0;sq<2;++sq){
                        short4v vv;
                        #pragma unroll
                        for (int i=0;i<4;++i) vv[i] = (short)f2b(acc[sq][c][i] + bv);
                        *(short4v*)&XBp[sq][lr*XSTR + c*16 + lg*4] = vv;   // VT'[d=c*16+lr][t=lg*4..+3]
                    }
                }
            }
        }
    }
    LGKM0;

    // MFMA attention per head, both seqs (rows>=12 reads are benign overruns, masked downstream)
    {
        const bf16x8 bz = (bf16x8){0,0,0,0,0,0,0,0};
        #pragma unroll
        for (int hd=0; hd<4; ++hd){
            #pragma unroll
            for (int sq=0;sq<2;++sq){
                bf16x8 ak = bz, bq = bz;
                if (lg < 2){
                    ak = *(const bf16x8*)&SCp[sq][lr*SSTR + 64 + hd*16 + lg*8];
                    bq = *(const bf16x8*)&SCp[sq][lr*SSTR +      hd*16 + lg*8];
                }
                f32x4 st = __builtin_amdgcn_mfma_f32_16x16x32_bf16(ak, bq, (f32x4){0.f,0.f,0.f,0.f}, 0,0,0);
                float s0=st[0], s1v=st[1], s2=st[2], s3=st[3];
                if (lg == 3){ s0=s1v=s2=s3=-1e30f; }
                float mx = fmaxf(fmaxf(s0,s1v), fmaxf(s2,s3));
                mx = fmaxf(mx, __shfl_xor(mx, 16, 64));
                mx = fmaxf(mx, __shfl_xor(mx, 32, 64));
                float p0 = __expf(s0-mx), p1 = __expf(s1v-mx), p2 = __expf(s2-mx), p3 = __expf(s3-mx);
                float den = p0+p1+p2+p3;
                den += __shfl_xor(den, 16, 64);
                den += __shfl_xor(den, 32, 64);
                float inv = __builtin_amdgcn_rcpf(den);
                float q0 = __shfl_down(p0, 16, 64), q1 = __shfl_down(p1, 16, 64);
                float q2 = __shfl_down(p2, 16, 64), q3 = __shfl_down(p3, 16, 64);
                bf16x8 pb;
                {
                    float lo0 = (lg==0)? p0 : (lg==1)? q0 : 0.f;
                    float lo1 = (lg==0)? p1 : (lg==1)? q1 : 0.f;
                    float lo2 = (lg==0)? p2 : (lg==1)? q2 : 0.f;
                    float lo3 = (lg==0)? p3 : (lg==1)? q3 : 0.f;
                    float hi0 = (lg==0)? q0 : 0.f;
                    float hi1 = (lg==0)? q1 : 0.f;
                    float hi2 = (lg==0)? q2 : 0.f;
                    float hi3 = (lg==0)? q3 : 0.f;
                    pb[0]=(short)f2b(lo0); pb[1]=(short)f2b(lo1); pb[2]=(short)f2b(lo2); pb[3]=(short)f2b(lo3);
                    pb[4]=(short)f2b(hi0); pb[5]=(short)f2b(hi1); pb[6]=(short)f2b(hi2); pb[7]=(short)f2b(hi3);
                }
                bf16x8 av = bz;
                if (lg < 2) av = *(const bf16x8*)&XBp[sq][lr*XSTR + hd*16 + lg*8];
                f32x4 ot = __builtin_amdgcn_mfma_f32_16x16x32_bf16(av, pb, (f32x4){0.f,0.f,0.f,0.f}, 0,0,0);
                short4v ow;
                #pragma unroll
                for (int i=0;i<4;++i) ow[i] = (short)f2b(ot[i]*inv);
                *(short4v*)&XBp[sq][lr*XSTR + hd*16 + lg*4] = ow;
            }
        }
    }
    LGKM0;

    // proj + residual -> s1 (shared weight frags)
    float s1[2][4][4];
    {
        bf16x8 a0[2], a1[2];
        #pragma unroll
        for (int sq=0;sq<2;++sq){
            a0[sq] = *(const bf16x8*)&XBp[sq][lr*XSTR + 0*32 + lg*8];
            a1[sq] = *(const bf16x8*)&XBp[sq][lr*XSTR + 1*32 + lg*8];
        }
        f32x4 pacc[2][4];
        #pragma unroll
        for (int sq=0;sq<2;++sq)
            #pragma unroll
            for (int ct=0;ct<4;++ct) pacc[sq][ct] = (f32x4){0.f,0.f,0.f,0.f};
        #pragma unroll
        for (int ct=0;ct<4;++ct){
            bf16x8 b0 = *(const bf16x8*)&wto[(ct*16+lr)*64 + 0*32 + lg*8];
            bf16x8 b1v= *(const bf16x8*)&wto[(ct*16+lr)*64 + 1*32 + lg*8];
            #pragma unroll
            for (int sq=0;sq<2;++sq){
                pacc[sq][ct] = __builtin_amdgcn_mfma_f32_16x16x32_bf16(a0[sq], b0, pacc[sq][ct], 0,0,0);
                pacc[sq][ct] = __builtin_amdgcn_mfma_f32_16x16x32_bf16(a1[sq], b1v, pacc[sq][ct], 0,0,0);
            }
        }
        #pragma unroll
        for (int sq=0;sq<2;++sq)
            #pragma unroll
            for (int ct=0;ct<4;++ct){
                float bv = bo[ct*16+lr];
                #pragma unroll
                for (int i=0;i<4;++i)
                    s1[sq][ct][i] = res[sq][ct][i] + pacc[sq][ct][i] + bv;
            }
    }

    // LN2 -> XB (both seqs)
    #pragma unroll
    for (int sq=0;sq<2;++sq){
        float sm[4], sqr[4];
        #pragma unroll
        for (int i=0;i<4;++i){
            sm[i]  = s1[sq][0][i]+s1[sq][1][i]+s1[sq][2][i]+s1[sq][3][i];
            sqr[i] = s1[sq][0][i]*s1[sq][0][i]+s1[sq][1][i]*s1[sq][1][i]
                   + s1[sq][2][i]*s1[sq][2][i]+s1[sq][3][i]*s1[sq][3][i];
        }
        #pragma unroll
        for (int m=1;m<16;m<<=1){
            #pragma unroll
            for (int i=0;i<4;++i){
                sm[i]  += __shfl_xor(sm[i], m, 64);
                sqr[i] += __shfl_xor(sqr[i], m, 64);
            }
        }
        #pragma unroll
        for (int nt=0;nt<4;++nt){
            float gg = ln2g[nt*16+lr], oo = ln2b[nt*16+lr];
            #pragma unroll
            for (int i=0;i<4;++i){
                float mn = sm[i]*(1.0f/64.0f);
                float var = sqr[i]*(1.0f/64.0f) - mn*mn;
                float rs = rsqrtf(var + 1e-5f);
                XBp[sq][(lg*4+i)*XSTR + nt*16 + lr] = f2b((s1[sq][nt][i]-mn)*rs*gg + oo);
            }
        }
    }
    LGKM0;

    // FFN: two 128-wide halves; HID stores guarded to rows<12; shared weight frags
    f32x4 oacc[2][4];
    #pragma unroll
    for (int sq=0;sq<2;++sq)
        #pragma unroll
        for (int ct=0;ct<4;++ct) oacc[sq][ct] = (f32x4){0.f,0.f,0.f,0.f};
    {
        bf16x8 a0[2], a1[2];
        #pragma unroll
        for (int sq=0;sq<2;++sq){
            a0[sq] = *(const bf16x8*)&XBp[sq][lr*XSTR + 0*32 + lg*8];
            a1[sq] = *(const bf16x8*)&XBp[sq][lr*XSTR + 1*32 + lg*8];
        }
        #pragma unroll
        for (int half=0; half<2; ++half){
            LGKM0;   // HID region reuse guard
            #pragma unroll
            for (int q=0; q<2; ++q){
                f32x4 facc[2][4];
                #pragma unroll
                for (int sq=0;sq<2;++sq)
                    #pragma unroll
                    for (int c=0;c<4;++c) facc[sq][c] = (f32x4){0.f,0.f,0.f,0.f};
                #pragma unroll
                for (int c=0;c<4;++c){
                    int ct = half*8 + q*4 + c;
                    bf16x8 b0 = *(const bf16x8*)&wt1[(ct*16+lr)*64 + 0*32 + lg*8];
                    bf16x8 b1v= *(const bf16x8*)&wt1[(ct*16+lr)*64 + 1*32 + lg*8];
                    #pragma unroll
                    for (int sq=0;sq<2;++sq){
                        facc[sq][c] = __builtin_amdgcn_mfma_f32_16x16x32_bf16(a0[sq], b0, facc[sq][c], 0,0,0);
                        facc[sq][c] = __builtin_amdgcn_mfma_f32_16x16x32_bf16(a1[sq], b1v, facc[sq][c], 0,0,0);
                    }
                }
                if (lg < 3){
                    #pragma unroll
                    for (int c=0;c<4;++c){
                        int ct = half*8 + q*4 + c;
                        float bv = fb1[ct*16+lr];
                        #pragma unroll
                        for (int sq=0;sq<2;++sq)
                            #pragma unroll
                            for (int i=0;i<4;++i){
                                float xv = facc[sq][c][i] + bv;
                                float x2 = xv*xv;
                                float z  = xv*(1.5957691216f + 0.0713548162f*x2);
                                float ez = __expf(-z);
                                SCp[sq][(lg*4+i)*SSTR + (q*4+c)*16 + lr] = f2b(xv * __builtin_amdgcn_rcpf(1.0f + ez));
                            }
                    }
                }
            }
            LGKM0;
            #pragma unroll
            for (int ks=0;ks<4;++ks){
                bf16x8 af[2];
                #pragma unroll
                for (int sq=0;sq<2;++sq)
                    af[sq] = *(const bf16x8*)&SCp[sq][lr*SSTR + ks*32 + lg*8];
                #pragma unroll
                for (int ct=0;ct<4;++ct){
                    bf16x8 bfr = *(const bf16x8*)&wt2[(ct*16+lr)*256 + half*128 + ks*32 + lg*8];
                    #pragma unroll
                    for (int sq=0;sq<2;++sq)
                        oacc[sq][ct] = __builtin_amdgcn_mfma_f32_16x16x32_bf16(af[sq], bfr, oacc[sq][ct], 0,0,0);
                }
            }
        }
    }

    // residual + mean over t (both seqs)
    #pragma unroll
    for (int sq=0;sq<2;++sq)
        #pragma unroll
        for (int ct=0;ct<4;++ct){
            float bv = fb2[ct*16+lr];
            float part = 0.f;
            #pragma unroll
            for (int i=0;i<4;++i){
                if (lg*4+i < 12) part += s1[sq][ct][i] + oacc[sq][ct][i] + bv;
            }
            part += __shfl_xor(part, 16, 64);
            part += __shfl_xor(part, 32, 64);
            if (lg == 0) out[(size_t)(gbase+sq)*64 + ct*16 + lr] = part*(1.0f/12.0f);
        }
}

// ----------------------------------------------------------------
extern "C" void kernel_launch(void* const* d_in, const int* in_sizes, int n_in,
                              void* d_out, int out_size, void* d_ws, size_t ws_size,
                              hipStream_t stream) {
    const float* x      = (const float*)d_in[0];
    const int*   r_ei   = (const int*)  d_in[1];
    const float* r_ea   = (const float*)d_in[2];
    const int*   c_ei   = (const int*)  d_in[3];
    const float* c_ew   = (const float*)d_in[4];
    const float* rvWlin = (const float*)d_in[5];
    const float* rvblin = (const float*)d_in[6];
    const float* rvWupd = (const float*)d_in[7];
    const float* rvbupd = (const float*)d_in[8];
    const float* rvgate = (const float*)d_in[9];
    const float* rvlw   = (const float*)d_in[10];
    const float* csWlin = (const float*)d_in[11];
    const float* csblin = (const float*)d_in[12];
    const float* csWupd = (const float*)d_in[13];
    const float* csbupd = (const float*)d_in[14];
    const float* csgate = (const float*)d_in[15];
    const float* cslw   = (const float*)d_in[16];
    const float* fuW1   = (const float*)d_in[17];
    const float* fub1   = (const float*)d_in[18];
    const float* fuW2   = (const float*)d_in[19];
    const float* fub2   = (const float*)d_in[20];
    const float* ln1g   = (const float*)d_in[21];
    const float* ln1b   = (const float*)d_in[22];
    const float* ln2g   = (const float*)d_in[23];
    const float* ln2b   = (const float*)d_in[24];
    const float* Wqkv   = (const float*)d_in[25];
    const float* bqkv   = (const float*)d_in[26];
    const float* Wo     = (const float*)d_in[27];
    const float* bo     = (const float*)d_in[28];
    const float* ffW1   = (const float*)d_in[29];
    const float* ffb1   = (const float*)d_in[30];
    const float* ffW2   = (const float*)d_in[31];
    const float* ffb2   = (const float*)d_in[32];

    float* wsp  = (float*)d_ws;
    unsigned short* FNY_b = (unsigned short*)wsp;                    // causal y bf16, then FUSED bf16
    unsigned short* FNA_b = (unsigned short*)(wsp + 12288000);       // causal aggr bf16
    unsigned short* XG_b  = (unsigned short*)(wsp + 12288000 + 6144000); // gathered x bf16
    unsigned short* WS_b  = (unsigned short*)(wsp + 24576000);       // watershed mean bf16
    unsigned short* WSY_b = (unsigned short*)(wsp + 26112000);       // river y bf16
    unsigned short* WSA_b = (unsigned short*)(wsp + 27648000);       // river aggr bf16
    float* WSU  = wsp + 29184000;                                    // CSR scratch, then river u bf16
    unsigned short* WSU_b = (unsigned short*)WSU;
    unsigned short* wt = (unsigned short*)(wsp + 30720000);
    float* outp = (float*)d_out;

    int* ibase  = (int*)WSU;
    int* cnt_c  = ibase;
    int* cnt_r  = ibase + 8000;
    int* off_c  = ibase + 9000;
    int* off_r  = ibase + 17001;
    int* cur_c  = ibase + 18002;
    int* cur_r  = ibase + 26002;
    int* eidx_c = ibase + 27002;
    int* eidx_r = ibase + 51002;
    float* mw_c = (float*)(ibase + 53002);
    float* mw_r = (float*)(ibase + 77002);

    const int* c_src = c_ei;
    const int* c_dst = c_ei + EC_;
    const int* r_src = r_ei;
    const int* r_dst = r_ei + ER_;

    hipMemsetAsync(cnt_c, 0, 9000*sizeof(int), stream);

    k_prepw<<<336, 256, 0, stream>>>(Wqkv, Wo, ffW1, ffW2, csWlin, rvWlin, csWupd, rvWupd,
                                     fuW1, fuW2, wt);
    k_mwhist<<<(EC_+ER_+255)/256, 256, 0, stream>>>(c_dst, r_dst, c_ew, cslw, csgate,
                                                    r_ea, rvlw, rvgate, mw_c, mw_r, cnt_c, cnt_r);
    k_scan<<<2, 256, 0, stream>>>(cnt_c, off_c, cur_c, cnt_r, off_r, cur_r);
    k_fill<<<(EC_+ER_+255)/256, 256, 0, stream>>>(c_dst, r_dst, cur_c, cur_r, eidx_c, eidx_r);

    // single-pass node linear: causal y + xg + ws-mean + river y
    k_lin<<<3000, 256, 0, stream>>>(x, wt+49152, csblin, wt+53248, rvblin,
                                    FNY_b, WSY_b, XG_b, WS_b);

    // merged gather-aggregation (no atomics)
    k_gaggr2<<<54000, 256, 0, stream>>>(FNY_b, c_src, eidx_c, off_c, mw_c, FNA_b,
                                        WSY_b, r_src, eidx_r, off_r, mw_r, WSA_b);

    // river update (clobbers CSR scratch -> OK, consumers done)
    k_upd16<<<375, 256, 0, stream>>>(WSA_b, WS_b, wt+65536, rvbupd, WSU_b);

    // fused causal update + fusion MLP -> FUSED bf16 (into FNY region)
    k_updfus<<<3000, 256, 0, stream>>>(FNA_b, XG_b, wt+57344, csbupd, WSU_b,
                                       wt+73728, fub1, wt+81920, fub2, FNY_b);

    // 2-seq-per-wave MFMA transformer (12-row SC)
    k_xformer<<<2000, 256, 0, stream>>>(FNY_b,
                                        wt, wt+12288, wt+16384, wt+32768,
                                        bqkv, bo, ffb1, ffb2,
                                        ln1g, ln1b, ln2g, ln2b,
                                        outp);
}